// Round 5
// baseline (639.561 us; speedup 1.0000x reference)
//
#include <hip/hip_runtime.h>
#include <hip/hip_bf16.h>

typedef __attribute__((ext_vector_type(8))) short short8;
typedef __attribute__((ext_vector_type(4))) float f32x4;
typedef unsigned short u16;

#define TTOK 4096
#define DMOD 512
#define DFFN 2048
#define NEXP 8
#define HEXP 1024

__device__ __forceinline__ u16 to_bf16(float f) {
    union { __hip_bfloat16 h; u16 u; } cv;
    cv.h = __float2bfloat16(f);
    return cv.u;
}

// gelu(x) = x * sigmoid(2*c*(x + 0.044715x^3)) -- one v_exp_f32, no libm tanh
__device__ __forceinline__ float gelu_tanh(float x) {
    const float c = 0.7978845608028654f;
    float y = c * (x + 0.044715f * x * x * x);
    return x / (1.0f + __expf(-2.0f * y));
}

__device__ __forceinline__ float4 ld_bf4(const u16* p) {
    ushort4 u = *(const ushort4*)p;
    union { unsigned i; float f; } a, b, c, d;
    a.i = (unsigned)u.x << 16; b.i = (unsigned)u.y << 16;
    c.i = (unsigned)u.z << 16; d.i = (unsigned)u.w << 16;
    return make_float4(a.f, b.f, c.f, d.f);
}

// ---------------- all 4 weight transposes (fp32 [R,C] -> bf16 [C,R]) in ONE launch ----------------
__global__ __launch_bounds__(256) void transpose_all(
    const float* __restrict__ fc1_w, const float* __restrict__ fc2_w,
    const float* __restrict__ w1, const float* __restrict__ w2,
    u16* __restrict__ fc1t, u16* __restrict__ fc2t,
    u16* __restrict__ w1t, u16* __restrict__ w2t)
{
    __shared__ float tile[32][33];
    int b = blockIdx.x;
    const float* in; u16* out; int R, C, cb, rb;
    if (b < 1024)      { in = fc1_w; out = fc1t; R = 512;  C = 2048; cb = b & 63; rb = b >> 6; }
    else if (b < 2048) { b -= 1024; in = fc2_w; out = fc2t; R = 2048; C = 512;  cb = b & 15; rb = b >> 4; }
    else if (b < 6144) { b -= 2048; int z = b >> 9; b &= 511;
        in = w1 + (size_t)z * DMOD * HEXP; out = w1t + (size_t)z * DMOD * HEXP;
        R = 512;  C = 1024; cb = b & 31; rb = b >> 5; }
    else               { b -= 6144; int z = b >> 9; b &= 511;
        in = w2 + (size_t)z * HEXP * DMOD; out = w2t + (size_t)z * HEXP * DMOD;
        R = 1024; C = 512;  cb = b & 15; rb = b >> 4; }
    int c0 = cb * 32, r0 = rb * 32;
    int tx = threadIdx.x & 31, ty = threadIdx.x >> 5;
#pragma unroll
    for (int i = 0; i < 32; i += 8)
        tile[ty + i][tx] = in[(size_t)(r0 + ty + i) * C + c0 + tx];
    __syncthreads();
#pragma unroll
    for (int i = 0; i < 32; i += 8)
        out[(size_t)(c0 + ty + i) * R + r0 + tx] = to_bf16(tile[tx][ty + i]);
}

// ---------------- prep: LN(x2) + feat + router top-2 + bucketing ----------------
__global__ __launch_bounds__(256) void prep_kernel(
    const float* __restrict__ hidden, const float* __restrict__ raw,
    const float* __restrict__ ln_g, const float* __restrict__ ln_b,
    const float* __restrict__ pre_g, const float* __restrict__ pre_b,
    const float* __restrict__ feat_w, const float* __restrict__ feat_b,
    const float* __restrict__ router_w, const float* __restrict__ router_b,
    u16* __restrict__ xs, float* __restrict__ xbuf, float* __restrict__ featbuf,
    int* __restrict__ cnt, int* __restrict__ slots,
    float* __restrict__ gslot, int* __restrict__ eslot)
{
    const int t = blockIdx.x, tid = threadIdx.x;
    const int lane = tid & 63, wid = tid >> 6;
    __shared__ float sred[4], qred[4], raw_sh[16], logit_sh[8], plred[4][8];

    const float* hrow = hidden + (size_t)t * DMOD;
    float h0 = hrow[tid], h1 = hrow[tid + 256];
    float s = h0 + h1, q = h0 * h0 + h1 * h1;
#pragma unroll
    for (int off = 32; off > 0; off >>= 1) { s += __shfl_down(s, off); q += __shfl_down(q, off); }
    if (lane == 0) { sred[wid] = s; qred[wid] = q; }
    if (tid < 16) raw_sh[tid] = raw[(size_t)t * 16 + tid];
    __syncthreads();

    float mean = (sred[0] + sred[1] + sred[2] + sred[3]) * (1.0f / 512.0f);
    float var  = (qred[0] + qred[1] + qred[2] + qred[3]) * (1.0f / 512.0f) - mean * mean;
    float rstd = rsqrtf(var + 1e-5f);
    float xn0 = (h0 - mean) * rstd, xn1 = (h1 - mean) * rstd;
    float x0 = xn0 * ln_g[tid] + ln_b[tid];
    float x1 = xn1 * ln_g[tid + 256] + ln_b[tid + 256];
    xs[(size_t)t * DMOD + tid]       = to_bf16(xn0 * pre_g[tid] + pre_b[tid]);
    xs[(size_t)t * DMOD + tid + 256] = to_bf16(xn1 * pre_g[tid + 256] + pre_b[tid + 256]);
    xbuf[(size_t)t * DMOD + tid]       = x0;
    xbuf[(size_t)t * DMOD + tid + 256] = x1;

    float pl[8];
#pragma unroll
    for (int e = 0; e < 8; ++e)
        pl[e] = x0 * router_w[tid * 8 + e] + x1 * router_w[(tid + 256) * 8 + e];
#pragma unroll
    for (int e = 0; e < 8; ++e) {
        float v = pl[e];
#pragma unroll
        for (int off = 32; off > 0; off >>= 1) v += __shfl_down(v, off);
        if (lane == 0) plred[wid][e] = v;
    }

    if (tid < 64) {
        float fv = feat_b[tid];
#pragma unroll
        for (int f = 0; f < 16; ++f) fv += raw_sh[f] * feat_w[f * 64 + tid];
        featbuf[(size_t)t * 64 + tid] = fv;
    }
    __syncthreads();
    if (tid < 8)
        logit_sh[tid] = plred[0][tid] + plred[1][tid] + plred[2][tid] + plred[3][tid] + router_b[tid];
    __syncthreads();

    if (tid == 0) {
        float v0 = -1e30f, v1 = -1e30f; int i0 = 0, i1 = 0;
#pragma unroll
        for (int e = 0; e < 8; ++e) {
            float v = logit_sh[e];
            if (v > v0) { v1 = v0; i1 = i0; v0 = v; i0 = e; }
            else if (v > v1) { v1 = v; i1 = e; }
        }
        float g1 = 1.0f / (1.0f + __expf(v0 - v1));
        float g0 = 1.0f - g1;
        int p0 = atomicAdd(&cnt[i0], 1);
        slots[i0 * TTOK + p0] = 2 * t;
        int p1 = atomicAdd(&cnt[i1], 1);
        slots[i1 * TTOK + p1] = 2 * t + 1;
        gslot[2 * t] = g0;     eslot[2 * t] = i0;
        gslot[2 * t + 1] = g1; eslot[2 * t + 1] = i1;
    }
}

// ---------------- film: xin = x*(1+gamma)+beta, tiled 16 tokens/block ----------------
__global__ __launch_bounds__(256) void film_kernel(
    const float* __restrict__ xbuf, const float* __restrict__ featbuf,
    const float* __restrict__ film_w, const float* __restrict__ film_b,
    u16* __restrict__ xin)
{
    const int t0 = blockIdx.x * 16, tid = threadIdx.x;
    __shared__ float fs[16 * 64];
#pragma unroll
    for (int i = 0; i < 4; ++i)
        fs[tid + i * 256] = featbuf[(size_t)t0 * 64 + tid + i * 256];
    __syncthreads();

    float acc[16][4];
#pragma unroll
    for (int t = 0; t < 16; ++t) { acc[t][0] = 0.f; acc[t][1] = 0.f; acc[t][2] = 0.f; acc[t][3] = 0.f; }

    for (int j = 0; j < 64; ++j) {
        const float* fw = film_w + (size_t)j * 1024 + tid;
        float w0 = fw[0], w1 = fw[256], w2 = fw[512], w3 = fw[768];
#pragma unroll
        for (int t = 0; t < 16; ++t) {
            float fv = fs[t * 64 + j];
            acc[t][0] += fv * w0; acc[t][1] += fv * w1;
            acc[t][2] += fv * w2; acc[t][3] += fv * w3;
        }
    }
    float b0 = film_b[tid], b1 = film_b[tid + 256], b2 = film_b[tid + 512], b3 = film_b[tid + 768];
#pragma unroll
    for (int t = 0; t < 16; ++t) {
        size_t row = (size_t)(t0 + t) * DMOD;
        float xv0 = xbuf[row + tid], xv1 = xbuf[row + tid + 256];
        xin[row + tid]       = to_bf16(xv0 * (1.0f + acc[t][0] + b0) + acc[t][2] + b2);
        xin[row + tid + 256] = to_bf16(xv1 * (1.0f + acc[t][1] + b1) + acc[t][3] + b3);
    }
}

// ---------------- 128x128 MFMA tile, BK=64, register-prefetch pipeline ----------------
// NOTE round-4 lesson: do NOT pair this with an occupancy clamp. The pipeline keeps
// 8 uint4 prefetch values (32 VGPRs) live across barriers; __launch_bounds__(256,3)
// forced the allocator to 72 VGPRs -> every prefetch spilled to scratch (WRITE_SIZE
// 32MB -> 126MB). Plain (256) lets the allocator size the file; spills gone.
template<int KLEN>
__device__ __forceinline__ void gemm_pipe(
    const u16* __restrict__ A, int ldA,
    const u16* __restrict__ Bt, int ldB,
    const int* arow, const int* brow,
    f32x4 acc[4][4], u16* As, u16* Bs)
{
    const int tid = threadIdx.x, lane = tid & 63, w = tid >> 6;
    const int l7 = lane & 7, r8 = lane >> 3;
    const int cl = l7 ^ r8;                       // logical chunk this lane stages
    const u16* ga[4]; const u16* gb[4];
#pragma unroll
    for (int c = 0; c < 4; ++c) {
        ga[c] = A + (size_t)arow[c] * ldA + cl * 8;
        gb[c] = Bt + (size_t)brow[c] * ldB + cl * 8;
    }
    u16* aw = As + (w * 32 + r8) * 64 + l7 * 8;   // phys chunk l7 of row w*32+r8(+c*8)
    u16* bw = Bs + (w * 32 + r8) * 64 + l7 * 8;

    uint4 ra[4], rb[4];
#pragma unroll
    for (int c = 0; c < 4; ++c) { ra[c] = *(const uint4*)ga[c]; rb[c] = *(const uint4*)gb[c]; }

#pragma unroll
    for (int mi = 0; mi < 4; ++mi)
#pragma unroll
        for (int nj = 0; nj < 4; ++nj) {
            acc[mi][nj][0] = 0.f; acc[mi][nj][1] = 0.f;
            acc[mi][nj][2] = 0.f; acc[mi][nj][3] = 0.f;
        }
    const int wm = (w >> 1) * 64, wn = (w & 1) * 64;
    const int row16 = lane & 15, kc = lane >> 4;
    int aoff[4], boff[4];
#pragma unroll
    for (int mi = 0; mi < 4; ++mi) aoff[mi] = (wm + mi * 16 + row16) * 64;
#pragma unroll
    for (int nj = 0; nj < 4; ++nj) boff[nj] = (wn + nj * 16 + row16) * 64;
    const int cp0 = (kc ^ l7) * 8, cp1 = ((4 + kc) ^ l7) * 8;

    constexpr int ITERS = KLEN / 64;
#pragma unroll 2
    for (int k = 0; k < ITERS; ++k) {
        __syncthreads();                          // readers of prev tile done (lgkm only)
#pragma unroll
        for (int c = 0; c < 4; ++c) {
            *(uint4*)(aw + c * 512) = ra[c];      // vmcnt wait lands here (loads ~1 iter old)
            *(uint4*)(bw + c * 512) = rb[c];
        }
        __syncthreads();                          // ds_writes visible
        if (k + 1 < ITERS) {
#pragma unroll
            for (int c = 0; c < 4; ++c) {         // prefetch tile k+1; completes during MFMA
                ra[c] = *(const uint4*)(ga[c] + (k + 1) * 64);
                rb[c] = *(const uint4*)(gb[c] + (k + 1) * 64);
            }
        }
        short8 af[4], bfr[4];
#pragma unroll
        for (int mi = 0; mi < 4; ++mi) af[mi] = *(const short8*)(As + aoff[mi] + cp0);
#pragma unroll
        for (int nj = 0; nj < 4; ++nj) bfr[nj] = *(const short8*)(Bs + boff[nj] + cp0);
#pragma unroll
        for (int mi = 0; mi < 4; ++mi)
#pragma unroll
            for (int nj = 0; nj < 4; ++nj)
                acc[mi][nj] = __builtin_amdgcn_mfma_f32_16x16x32_bf16(af[mi], bfr[nj], acc[mi][nj], 0, 0, 0);
#pragma unroll
        for (int mi = 0; mi < 4; ++mi) af[mi] = *(const short8*)(As + aoff[mi] + cp1);
#pragma unroll
        for (int nj = 0; nj < 4; ++nj) bfr[nj] = *(const short8*)(Bs + boff[nj] + cp1);
#pragma unroll
        for (int mi = 0; mi < 4; ++mi)
#pragma unroll
            for (int nj = 0; nj < 4; ++nj)
                acc[mi][nj] = __builtin_amdgcn_mfma_f32_16x16x32_bf16(af[mi], bfr[nj], acc[mi][nj], 0, 0, 0);
    }
}

// ---------------- stage1: ffn1 (z==8) + moe1 (z<8) ----------------
__global__ __launch_bounds__(256) void stage1_kernel(
    const u16* __restrict__ xs, const u16* __restrict__ fc1t, const float* __restrict__ fc1_b,
    u16* __restrict__ h1,
    const u16* __restrict__ xin, const u16* __restrict__ w1t, const float* __restrict__ b1,
    const int* __restrict__ cnt, const int* __restrict__ slots, u16* __restrict__ hbuf)
{
    __shared__ __align__(16) u16 As[8192], Bs[8192];
    const int tid = threadIdx.x, lane = tid & 63, w = tid >> 6;
    const int wm = (w >> 1) * 64, wn = (w & 1) * 64;
    const int cb = lane & 15, rq = (lane >> 4) * 4;
    const int rbase = w * 32 + (lane >> 3);
    int arow[4], brow[4];
    f32x4 acc[4][4];

    if (blockIdx.z == 8) {
        const int m0 = blockIdx.x * 128, n0 = blockIdx.y * 128;
#pragma unroll
        for (int c = 0; c < 4; ++c) { arow[c] = m0 + rbase + c * 8; brow[c] = n0 + rbase + c * 8; }
        gemm_pipe<DMOD>(xs, DMOD, fc1t, DMOD, arow, brow, acc, As, Bs);
#pragma unroll
        for (int mi = 0; mi < 4; ++mi)
#pragma unroll
            for (int nj = 0; nj < 4; ++nj) {
                int col = n0 + wn + nj * 16 + cb;
                float bias = fc1_b[col];
#pragma unroll
                for (int r = 0; r < 4; ++r) {
                    int row = m0 + wm + mi * 16 + rq + r;
                    h1[(size_t)row * DFFN + col] = to_bf16(gelu_tanh(acc[mi][nj][r] + bias));
                }
            }
    } else {
        if (blockIdx.y >= 8) return;
        const int e = blockIdx.z, ce = cnt[e];
        const int m0 = blockIdx.x * 128;
        if (m0 >= ce) return;
        const int n0 = blockIdx.y * 128;
        const int* sl = slots + e * TTOK;
#pragma unroll
        for (int c = 0; c < 4; ++c) {
            int p = m0 + rbase + c * 8; if (p > ce - 1) p = ce - 1;
            arow[c] = sl[p] >> 1;
            brow[c] = n0 + rbase + c * 8;
        }
        gemm_pipe<DMOD>(xin, DMOD, w1t + (size_t)e * HEXP * DMOD, DMOD, arow, brow, acc, As, Bs);
#pragma unroll
        for (int mi = 0; mi < 4; ++mi)
#pragma unroll
            for (int r = 0; r < 4; ++r) {
                int p = m0 + wm + mi * 16 + rq + r;
                if (p < ce) {
                    int slot = sl[p];
#pragma unroll
                    for (int nj = 0; nj < 4; ++nj) {
                        int col = n0 + wn + nj * 16 + cb;
                        hbuf[(size_t)slot * HEXP + col] = to_bf16(gelu_tanh(acc[mi][nj][r] + b1[e * HEXP + col]));
                    }
                }
            }
    }
}

// ---------------- stage2: ffn2 (z==8) + moe2 (z<8), split-K=2, bf16 partials ----------------
__global__ __launch_bounds__(256) void stage2_kernel(
    const u16* __restrict__ h1, const u16* __restrict__ fc2t,
    const u16* __restrict__ hbuf, const u16* __restrict__ w2t,
    const int* __restrict__ cnt, const int* __restrict__ slots,
    u16* __restrict__ pf, u16* __restrict__ pm)
{
    __shared__ __align__(16) u16 As[8192], Bs[8192];
    const int tid = threadIdx.x, lane = tid & 63, w = tid >> 6;
    const int wm = (w >> 1) * 64, wn = (w & 1) * 64;
    const int cb = lane & 15, rq = (lane >> 4) * 4;
    const int rbase = w * 32 + (lane >> 3);
    const int n0 = (blockIdx.y & 3) * 128, ks = blockIdx.y >> 2;
    int arow[4], brow[4];
    f32x4 acc[4][4];

    if (blockIdx.z == 8) {
        const int m0 = blockIdx.x * 128;
#pragma unroll
        for (int c = 0; c < 4; ++c) { arow[c] = m0 + rbase + c * 8; brow[c] = n0 + rbase + c * 8; }
        gemm_pipe<1024>(h1 + ks * 1024, DFFN, fc2t + ks * 1024, DFFN, arow, brow, acc, As, Bs);
        u16* dst = pf + (size_t)ks * TTOK * DMOD;
#pragma unroll
        for (int mi = 0; mi < 4; ++mi)
#pragma unroll
            for (int nj = 0; nj < 4; ++nj) {
                int col = n0 + wn + nj * 16 + cb;
#pragma unroll
                for (int r = 0; r < 4; ++r) {
                    int row = m0 + wm + mi * 16 + rq + r;
                    dst[(size_t)row * DMOD + col] = to_bf16(acc[mi][nj][r]);
                }
            }
    } else {
        const int e = blockIdx.z, ce = cnt[e];
        const int m0 = blockIdx.x * 128;
        if (m0 >= ce) return;
        const int* sl = slots + e * TTOK;
#pragma unroll
        for (int c = 0; c < 4; ++c) {
            int p = m0 + rbase + c * 8; if (p > ce - 1) p = ce - 1;
            arow[c] = sl[p];
            brow[c] = n0 + rbase + c * 8;
        }
        gemm_pipe<512>(hbuf + ks * 512, HEXP, w2t + (size_t)e * DMOD * HEXP + ks * 512, HEXP,
                       arow, brow, acc, As, Bs);
        u16* dst = pm + (size_t)ks * 2 * TTOK * DMOD;
#pragma unroll
        for (int mi = 0; mi < 4; ++mi)
#pragma unroll
            for (int r = 0; r < 4; ++r) {
                int p = m0 + wm + mi * 16 + rq + r;
                if (p < ce) {
                    int slot = sl[p];
#pragma unroll
                    for (int nj = 0; nj < 4; ++nj) {
                        int col = n0 + wn + nj * 16 + cb;
                        dst[(size_t)slot * DMOD + col] = to_bf16(acc[mi][nj][r]);
                    }
                }
            }
    }
}

// ---------------- combine: out = hidden + ffn2(+bias) + alpha*(gated moe(+bias)) ----------------
__global__ __launch_bounds__(256) void combine_kernel(
    const float* __restrict__ hidden, const u16* __restrict__ pf, const u16* __restrict__ pm,
    const float* __restrict__ fc2_b, const float* __restrict__ b2,
    const float* __restrict__ gslot, const int* __restrict__ eslot,
    const float* __restrict__ alpha, float* __restrict__ out)
{
    int i = blockIdx.x * 256 + threadIdx.x;     // float4 index over T*D/4
    int t = i >> 7, d = (i & 127) * 4;
    float a = alpha[0];
    float4 h = ((const float4*)hidden)[i];
    float4 bias = *(const float4*)(fc2_b + d);

    size_t fo = (size_t)t * DMOD + d;
    float4 f0 = ld_bf4(pf + fo), f1 = ld_bf4(pf + (size_t)TTOK * DMOD + fo);

    int s0 = 2 * t, s1 = 2 * t + 1;
    float g0 = gslot[s0], g1 = gslot[s1];
    int e0 = eslot[s0], e1 = eslot[s1];
    size_t mo0 = (size_t)s0 * DMOD + d, mo1 = (size_t)s1 * DMOD + d;
    const u16* pm1 = pm + (size_t)2 * TTOK * DMOD;
    float4 ma = ld_bf4(pm + mo0), mb = ld_bf4(pm1 + mo0);
    float4 mc = ld_bf4(pm + mo1), md = ld_bf4(pm1 + mo1);
    float4 ba = *(const float4*)(b2 + e0 * DMOD + d);
    float4 bb = *(const float4*)(b2 + e1 * DMOD + d);

    float4 o;
    o.x = h.x + f0.x + f1.x + bias.x + a * (g0 * (ma.x + mb.x + ba.x) + g1 * (mc.x + md.x + bb.x));
    o.y = h.y + f0.y + f1.y + bias.y + a * (g0 * (ma.y + mb.y + ba.y) + g1 * (mc.y + md.y + bb.y));
    o.z = h.z + f0.z + f1.z + bias.z + a * (g0 * (ma.z + mb.z + ba.z) + g1 * (mc.z + md.z + bb.z));
    o.w = h.w + f0.w + f1.w + bias.w + a * (g0 * (ma.w + mb.w + ba.w) + g1 * (mc.w + md.w + bb.w));
    ((float4*)out)[i] = o;
}

extern "C" void kernel_launch(void* const* d_in, const int* in_sizes, int n_in,
                              void* d_out, int out_size, void* d_ws, size_t ws_size,
                              hipStream_t stream)
{
    const float* hidden   = (const float*)d_in[0];
    const float* raw      = (const float*)d_in[1];
    const float* ln_g     = (const float*)d_in[2];
    const float* ln_b     = (const float*)d_in[3];
    const float* pre_g    = (const float*)d_in[4];
    const float* pre_b    = (const float*)d_in[5];
    const float* feat_w   = (const float*)d_in[6];
    const float* feat_b   = (const float*)d_in[7];
    const float* film_w   = (const float*)d_in[8];
    const float* film_b   = (const float*)d_in[9];
    const float* router_w = (const float*)d_in[10];
    const float* router_b = (const float*)d_in[11];
    const float* w1       = (const float*)d_in[12];
    const float* b1       = (const float*)d_in[13];
    const float* w2       = (const float*)d_in[14];
    const float* b2       = (const float*)d_in[15];
    const float* fc1_w    = (const float*)d_in[16];
    const float* fc1_b    = (const float*)d_in[17];
    const float* fc2_w    = (const float*)d_in[18];
    const float* fc2_b    = (const float*)d_in[19];
    const float* alpha    = (const float*)d_in[20];
    float* out = (float*)d_out;

    char* w = (char*)d_ws;
    auto alloc = [&](size_t b) { char* p = w; w += (b + 255) & ~(size_t)255; return p; };
    u16*  fc1t = (u16*)alloc((size_t)DFFN * DMOD * 2);
    u16*  fc2t = (u16*)alloc((size_t)DMOD * DFFN * 2);
    u16*  w1t  = (u16*)alloc((size_t)NEXP * HEXP * DMOD * 2);
    u16*  w2t  = (u16*)alloc((size_t)NEXP * DMOD * HEXP * 2);
    u16*  xs   = (u16*)alloc((size_t)TTOK * DMOD * 2);
    u16*  xin  = (u16*)alloc((size_t)TTOK * DMOD * 2);
    u16*  h1   = (u16*)alloc((size_t)TTOK * DFFN * 2);
    u16*  hb   = (u16*)alloc((size_t)2 * TTOK * HEXP * 2);
    u16*  pf   = (u16*)alloc((size_t)2 * TTOK * DMOD * 2);        // ffn2 partials (2 splits)
    u16*  pm   = (u16*)alloc((size_t)2 * 2 * TTOK * DMOD * 2);    // moe2 partials (2 splits)
    int*   cnt   = (int*)alloc(NEXP * 4);
    int*   slots = (int*)alloc((size_t)NEXP * TTOK * 4);
    float* gslot = (float*)alloc((size_t)2 * TTOK * 4);
    int*   eslot = (int*)alloc((size_t)2 * TTOK * 4);
    float* xbuf  = (float*)pm;      // fp32 [T,D]=8MB, consumed by film before stage2 writes pm
    float* featbuf = (float*)h1;    // 1MB, consumed by film before stage1 writes h1

    hipMemsetAsync(cnt, 0, NEXP * 4, stream);
    transpose_all<<<10240, 256, 0, stream>>>(fc1_w, fc2_w, w1, w2, fc1t, fc2t, w1t, w2t);
    prep_kernel<<<4096, 256, 0, stream>>>(hidden, raw, ln_g, ln_b, pre_g, pre_b,
        feat_w, feat_b, router_w, router_b, xs, xbuf, featbuf, cnt, slots, gslot, eslot);
    film_kernel<<<256, 256, 0, stream>>>(xbuf, featbuf, film_w, film_b, xin);
    stage1_kernel<<<dim3(32, 16, 9), 256, 0, stream>>>(xs, fc1t, fc1_b, h1,
        xin, w1t, b1, cnt, slots, hb);
    stage2_kernel<<<dim3(32, 8, 9), 256, 0, stream>>>(h1, fc2t, hb, w2t, cnt, slots, pf, pm);
    combine_kernel<<<2048, 256, 0, stream>>>(hidden, pf, pm, fc2_b, b2, gslot, eslot, alpha, out);
}

// Round 6
// 600.395 us; speedup vs baseline: 1.0652x; 1.0652x over previous
//
#include <hip/hip_runtime.h>
#include <hip/hip_bf16.h>

typedef __attribute__((ext_vector_type(8))) short short8;
typedef __attribute__((ext_vector_type(4))) float f32x4;
typedef unsigned short u16;

#define TTOK 4096
#define DMOD 512
#define DFFN 2048
#define NEXP 8
#define HEXP 1024

__device__ __forceinline__ u16 to_bf16(float f) {
    union { __hip_bfloat16 h; u16 u; } cv;
    cv.h = __float2bfloat16(f);
    return cv.u;
}

// gelu(x) = x * sigmoid(2*c*(x + 0.044715x^3)) -- one v_exp_f32, no libm tanh
__device__ __forceinline__ float gelu_tanh(float x) {
    const float c = 0.7978845608028654f;
    float y = c * (x + 0.044715f * x * x * x);
    return x / (1.0f + __expf(-2.0f * y));
}

__device__ __forceinline__ float4 ld_bf4(const u16* p) {
    ushort4 u = *(const ushort4*)p;
    union { unsigned i; float f; } a, b, c, d;
    a.i = (unsigned)u.x << 16; b.i = (unsigned)u.y << 16;
    c.i = (unsigned)u.z << 16; d.i = (unsigned)u.w << 16;
    return make_float4(a.f, b.f, c.f, d.f);
}

// ---------------- all 4 weight transposes (fp32 [R,C] -> bf16 [C,R]) in ONE launch ----------------
__global__ __launch_bounds__(256) void transpose_all(
    const float* __restrict__ fc1_w, const float* __restrict__ fc2_w,
    const float* __restrict__ w1, const float* __restrict__ w2,
    u16* __restrict__ fc1t, u16* __restrict__ fc2t,
    u16* __restrict__ w1t, u16* __restrict__ w2t)
{
    __shared__ float tile[32][33];
    int b = blockIdx.x;
    const float* in; u16* out; int R, C, cb, rb;
    if (b < 1024)      { in = fc1_w; out = fc1t; R = 512;  C = 2048; cb = b & 63; rb = b >> 6; }
    else if (b < 2048) { b -= 1024; in = fc2_w; out = fc2t; R = 2048; C = 512;  cb = b & 15; rb = b >> 4; }
    else if (b < 6144) { b -= 2048; int z = b >> 9; b &= 511;
        in = w1 + (size_t)z * DMOD * HEXP; out = w1t + (size_t)z * DMOD * HEXP;
        R = 512;  C = 1024; cb = b & 31; rb = b >> 5; }
    else               { b -= 6144; int z = b >> 9; b &= 511;
        in = w2 + (size_t)z * HEXP * DMOD; out = w2t + (size_t)z * HEXP * DMOD;
        R = 1024; C = 512;  cb = b & 15; rb = b >> 4; }
    int c0 = cb * 32, r0 = rb * 32;
    int tx = threadIdx.x & 31, ty = threadIdx.x >> 5;
#pragma unroll
    for (int i = 0; i < 32; i += 8)
        tile[ty + i][tx] = in[(size_t)(r0 + ty + i) * C + c0 + tx];
    __syncthreads();
#pragma unroll
    for (int i = 0; i < 32; i += 8)
        out[(size_t)(c0 + ty + i) * R + r0 + tx] = to_bf16(tile[tx][ty + i]);
}

// ---------------- prep: LN(x2) + feat + router top-2 + bucketing ----------------
__global__ __launch_bounds__(256) void prep_kernel(
    const float* __restrict__ hidden, const float* __restrict__ raw,
    const float* __restrict__ ln_g, const float* __restrict__ ln_b,
    const float* __restrict__ pre_g, const float* __restrict__ pre_b,
    const float* __restrict__ feat_w, const float* __restrict__ feat_b,
    const float* __restrict__ router_w, const float* __restrict__ router_b,
    u16* __restrict__ xs, float* __restrict__ xbuf, float* __restrict__ featbuf,
    int* __restrict__ cnt, int* __restrict__ slots,
    float* __restrict__ gslot, int* __restrict__ eslot)
{
    const int t = blockIdx.x, tid = threadIdx.x;
    const int lane = tid & 63, wid = tid >> 6;
    __shared__ float sred[4], qred[4], raw_sh[16], logit_sh[8], plred[4][8];

    const float* hrow = hidden + (size_t)t * DMOD;
    float h0 = hrow[tid], h1 = hrow[tid + 256];
    float s = h0 + h1, q = h0 * h0 + h1 * h1;
#pragma unroll
    for (int off = 32; off > 0; off >>= 1) { s += __shfl_down(s, off); q += __shfl_down(q, off); }
    if (lane == 0) { sred[wid] = s; qred[wid] = q; }
    if (tid < 16) raw_sh[tid] = raw[(size_t)t * 16 + tid];
    __syncthreads();

    float mean = (sred[0] + sred[1] + sred[2] + sred[3]) * (1.0f / 512.0f);
    float var  = (qred[0] + qred[1] + qred[2] + qred[3]) * (1.0f / 512.0f) - mean * mean;
    float rstd = rsqrtf(var + 1e-5f);
    float xn0 = (h0 - mean) * rstd, xn1 = (h1 - mean) * rstd;
    float x0 = xn0 * ln_g[tid] + ln_b[tid];
    float x1 = xn1 * ln_g[tid + 256] + ln_b[tid + 256];
    xs[(size_t)t * DMOD + tid]       = to_bf16(xn0 * pre_g[tid] + pre_b[tid]);
    xs[(size_t)t * DMOD + tid + 256] = to_bf16(xn1 * pre_g[tid + 256] + pre_b[tid + 256]);
    xbuf[(size_t)t * DMOD + tid]       = x0;
    xbuf[(size_t)t * DMOD + tid + 256] = x1;

    float pl[8];
#pragma unroll
    for (int e = 0; e < 8; ++e)
        pl[e] = x0 * router_w[tid * 8 + e] + x1 * router_w[(tid + 256) * 8 + e];
#pragma unroll
    for (int e = 0; e < 8; ++e) {
        float v = pl[e];
#pragma unroll
        for (int off = 32; off > 0; off >>= 1) v += __shfl_down(v, off);
        if (lane == 0) plred[wid][e] = v;
    }

    if (tid < 64) {
        float fv = feat_b[tid];
#pragma unroll
        for (int f = 0; f < 16; ++f) fv += raw_sh[f] * feat_w[f * 64 + tid];
        featbuf[(size_t)t * 64 + tid] = fv;
    }
    __syncthreads();
    if (tid < 8)
        logit_sh[tid] = plred[0][tid] + plred[1][tid] + plred[2][tid] + plred[3][tid] + router_b[tid];
    __syncthreads();

    if (tid == 0) {
        float v0 = -1e30f, v1 = -1e30f; int i0 = 0, i1 = 0;
#pragma unroll
        for (int e = 0; e < 8; ++e) {
            float v = logit_sh[e];
            if (v > v0) { v1 = v0; i1 = i0; v0 = v; i0 = e; }
            else if (v > v1) { v1 = v; i1 = e; }
        }
        float g1 = 1.0f / (1.0f + __expf(v0 - v1));
        float g0 = 1.0f - g1;
        int p0 = atomicAdd(&cnt[i0], 1);
        slots[i0 * TTOK + p0] = 2 * t;
        int p1 = atomicAdd(&cnt[i1], 1);
        slots[i1 * TTOK + p1] = 2 * t + 1;
        gslot[2 * t] = g0;     eslot[2 * t] = i0;
        gslot[2 * t + 1] = g1; eslot[2 * t + 1] = i1;
    }
}

// ---------------- film: 8 tokens/block, acc[8][4]=32 VGPRs (round-5 lesson: 16 tokens
// -> 64-float acc array spilled to scratch; bound the live set) ----------------
__global__ __launch_bounds__(256) void film_kernel(
    const float* __restrict__ xbuf, const float* __restrict__ featbuf,
    const float* __restrict__ film_w, const float* __restrict__ film_b,
    u16* __restrict__ xin)
{
    const int t0 = blockIdx.x * 8, tid = threadIdx.x;
    __shared__ float fs[8 * 64];
#pragma unroll
    for (int i = 0; i < 2; ++i)
        fs[tid + i * 256] = featbuf[(size_t)t0 * 64 + tid + i * 256];
    __syncthreads();

    float acc[8][4];
#pragma unroll
    for (int t = 0; t < 8; ++t) { acc[t][0] = 0.f; acc[t][1] = 0.f; acc[t][2] = 0.f; acc[t][3] = 0.f; }

    for (int j = 0; j < 64; ++j) {
        const float* fw = film_w + (size_t)j * 1024 + tid;
        float w0 = fw[0], w1 = fw[256], w2 = fw[512], w3 = fw[768];
#pragma unroll
        for (int t = 0; t < 8; ++t) {
            float fv = fs[t * 64 + j];
            acc[t][0] += fv * w0; acc[t][1] += fv * w1;
            acc[t][2] += fv * w2; acc[t][3] += fv * w3;
        }
    }
    float b0 = film_b[tid], b1 = film_b[tid + 256], b2 = film_b[tid + 512], b3 = film_b[tid + 768];
#pragma unroll
    for (int t = 0; t < 8; ++t) {
        size_t row = (size_t)(t0 + t) * DMOD;
        float xv0 = xbuf[row + tid], xv1 = xbuf[row + tid + 256];
        xin[row + tid]       = to_bf16(xv0 * (1.0f + acc[t][0] + b0) + acc[t][2] + b2);
        xin[row + tid + 256] = to_bf16(xv1 * (1.0f + acc[t][1] + b1) + acc[t][3] + b3);
    }
}

// ---------------- barrier-free direct-from-global MFMA GEMM core ----------------
// No LDS, no __syncthreads in the K-loop. Each lane loads its A/B fragments straight
// from global (16 rows x 64B contiguous per instruction -> same 64B L2 transactions
// as a staged load). Weights/activations are L2-resident (<=8MB). Depth-1 register
// double-buffer guarantees load/MFMA overlap; waves never collectively stall.
template<int NSTEPS>
__device__ __forceinline__ void gemm_direct(
    const u16* const ap[4], const u16* const bp[4], f32x4 acc[4][4])
{
#pragma unroll
    for (int mi = 0; mi < 4; ++mi)
#pragma unroll
        for (int nj = 0; nj < 4; ++nj) {
            acc[mi][nj][0] = 0.f; acc[mi][nj][1] = 0.f;
            acc[mi][nj][2] = 0.f; acc[mi][nj][3] = 0.f;
        }
    short8 ca[4], cb[4], na[4], nb[4];
#pragma unroll
    for (int i = 0; i < 4; ++i) {
        ca[i] = *(const short8*)(ap[i]);
        cb[i] = *(const short8*)(bp[i]);
    }
#pragma unroll
    for (int s = 0; s < NSTEPS; ++s) {
        if (s + 1 < NSTEPS) {
#pragma unroll
            for (int i = 0; i < 4; ++i) {
                na[i] = *(const short8*)(ap[i] + (s + 1) * 32);
                nb[i] = *(const short8*)(bp[i] + (s + 1) * 32);
            }
        }
#pragma unroll
        for (int mi = 0; mi < 4; ++mi)
#pragma unroll
            for (int nj = 0; nj < 4; ++nj)
                acc[mi][nj] = __builtin_amdgcn_mfma_f32_16x16x32_bf16(ca[mi], cb[nj], acc[mi][nj], 0, 0, 0);
#pragma unroll
        for (int i = 0; i < 4; ++i) { ca[i] = na[i]; cb[i] = nb[i]; }
    }
}

// ---------------- stage1: ffn1 (z==8) + moe1 (z<8) ----------------
__global__ __launch_bounds__(256) void stage1_kernel(
    const u16* __restrict__ xs, const u16* __restrict__ fc1t, const float* __restrict__ fc1_b,
    u16* __restrict__ h1,
    const u16* __restrict__ xin, const u16* __restrict__ w1t, const float* __restrict__ b1,
    const int* __restrict__ cnt, const int* __restrict__ slots, u16* __restrict__ hbuf)
{
    const int tid = threadIdx.x, lane = tid & 63, w = tid >> 6;
    const int wm = (w >> 1) * 64, wn = (w & 1) * 64;
    const int fr = lane & 15, kq = (lane >> 4) * 8;   // A/B fragment: row=lane&15, k=quad*8
    const int cb = lane & 15, rq = (lane >> 4) * 4;   // C fragment: col=lane&15, row=quad*4+r
    const u16* ap[4]; const u16* bp[4];
    f32x4 acc[4][4];

    if (blockIdx.z == 8) {
        const int m0 = blockIdx.x * 128, n0 = blockIdx.y * 128;
#pragma unroll
        for (int i = 0; i < 4; ++i) {
            ap[i] = xs   + (size_t)(m0 + wm + i * 16 + fr) * DMOD + kq;
            bp[i] = fc1t + (size_t)(n0 + wn + i * 16 + fr) * DMOD + kq;
        }
        gemm_direct<16>(ap, bp, acc);
#pragma unroll
        for (int mi = 0; mi < 4; ++mi)
#pragma unroll
            for (int nj = 0; nj < 4; ++nj) {
                int col = n0 + wn + nj * 16 + cb;
                float bias = fc1_b[col];
#pragma unroll
                for (int r = 0; r < 4; ++r) {
                    int row = m0 + wm + mi * 16 + rq + r;
                    h1[(size_t)row * DFFN + col] = to_bf16(gelu_tanh(acc[mi][nj][r] + bias));
                }
            }
    } else {
        if (blockIdx.y >= 8) return;
        const int e = blockIdx.z, ce = cnt[e];
        const int m0 = blockIdx.x * 128;
        if (m0 >= ce) return;
        const int n0 = blockIdx.y * 128;
        const int* sl = slots + e * TTOK;
        const u16* wte = w1t + (size_t)e * HEXP * DMOD;
#pragma unroll
        for (int i = 0; i < 4; ++i) {
            int p = m0 + wm + i * 16 + fr; if (p > ce - 1) p = ce - 1;
            ap[i] = xin + (size_t)(sl[p] >> 1) * DMOD + kq;
            bp[i] = wte + (size_t)(n0 + wn + i * 16 + fr) * DMOD + kq;
        }
        gemm_direct<16>(ap, bp, acc);
#pragma unroll
        for (int mi = 0; mi < 4; ++mi)
#pragma unroll
            for (int r = 0; r < 4; ++r) {
                int p = m0 + wm + mi * 16 + rq + r;
                if (p < ce) {
                    int slot = sl[p];
#pragma unroll
                    for (int nj = 0; nj < 4; ++nj) {
                        int col = n0 + wn + nj * 16 + cb;
                        hbuf[(size_t)slot * HEXP + col] = to_bf16(gelu_tanh(acc[mi][nj][r] + b1[e * HEXP + col]));
                    }
                }
            }
    }
}

// ---------------- stage2: ffn2 (z==8) + moe2 (z<8), split-K=2, bf16 partials ----------------
__global__ __launch_bounds__(256) void stage2_kernel(
    const u16* __restrict__ h1, const u16* __restrict__ fc2t,
    const u16* __restrict__ hbuf, const u16* __restrict__ w2t,
    const int* __restrict__ cnt, const int* __restrict__ slots,
    u16* __restrict__ pf, u16* __restrict__ pm)
{
    const int tid = threadIdx.x, lane = tid & 63, w = tid >> 6;
    const int wm = (w >> 1) * 64, wn = (w & 1) * 64;
    const int fr = lane & 15, kq = (lane >> 4) * 8;
    const int cb = lane & 15, rq = (lane >> 4) * 4;
    const int n0 = (blockIdx.y & 3) * 128, ks = blockIdx.y >> 2;
    const u16* ap[4]; const u16* bp[4];
    f32x4 acc[4][4];

    if (blockIdx.z == 8) {
        const int m0 = blockIdx.x * 128;
        const u16* A  = h1   + ks * 1024;
        const u16* Bt = fc2t + ks * 1024;
#pragma unroll
        for (int i = 0; i < 4; ++i) {
            ap[i] = A  + (size_t)(m0 + wm + i * 16 + fr) * DFFN + kq;
            bp[i] = Bt + (size_t)(n0 + wn + i * 16 + fr) * DFFN + kq;
        }
        gemm_direct<32>(ap, bp, acc);
        u16* dst = pf + (size_t)ks * TTOK * DMOD;
#pragma unroll
        for (int mi = 0; mi < 4; ++mi)
#pragma unroll
            for (int nj = 0; nj < 4; ++nj) {
                int col = n0 + wn + nj * 16 + cb;
#pragma unroll
                for (int r = 0; r < 4; ++r) {
                    int row = m0 + wm + mi * 16 + rq + r;
                    dst[(size_t)row * DMOD + col] = to_bf16(acc[mi][nj][r]);
                }
            }
    } else {
        const int e = blockIdx.z, ce = cnt[e];
        const int m0 = blockIdx.x * 128;
        if (m0 >= ce) return;
        const int* sl = slots + e * TTOK;
        const u16* A  = hbuf + ks * 512;
        const u16* Bt = w2t + (size_t)e * DMOD * HEXP + ks * 512;
#pragma unroll
        for (int i = 0; i < 4; ++i) {
            int p = m0 + wm + i * 16 + fr; if (p > ce - 1) p = ce - 1;
            ap[i] = A  + (size_t)sl[p] * HEXP + kq;
            bp[i] = Bt + (size_t)(n0 + wn + i * 16 + fr) * HEXP + kq;
        }
        gemm_direct<16>(ap, bp, acc);
        u16* dst = pm + (size_t)ks * 2 * TTOK * DMOD;
#pragma unroll
        for (int mi = 0; mi < 4; ++mi)
#pragma unroll
            for (int r = 0; r < 4; ++r) {
                int p = m0 + wm + mi * 16 + rq + r;
                if (p < ce) {
                    int slot = sl[p];
#pragma unroll
                    for (int nj = 0; nj < 4; ++nj) {
                        int col = n0 + wn + nj * 16 + cb;
                        dst[(size_t)slot * DMOD + col] = to_bf16(acc[mi][nj][r]);
                    }
                }
            }
    }
}

// ---------------- combine: out = hidden + ffn2(+bias) + alpha*(gated moe(+bias)) ----------------
__global__ __launch_bounds__(256) void combine_kernel(
    const float* __restrict__ hidden, const u16* __restrict__ pf, const u16* __restrict__ pm,
    const float* __restrict__ fc2_b, const float* __restrict__ b2,
    const float* __restrict__ gslot, const int* __restrict__ eslot,
    const float* __restrict__ alpha, float* __restrict__ out)
{
    int i = blockIdx.x * 256 + threadIdx.x;     // float4 index over T*D/4
    int t = i >> 7, d = (i & 127) * 4;
    float a = alpha[0];
    float4 h = ((const float4*)hidden)[i];
    float4 bias = *(const float4*)(fc2_b + d);

    size_t fo = (size_t)t * DMOD + d;
    float4 f0 = ld_bf4(pf + fo), f1 = ld_bf4(pf + (size_t)TTOK * DMOD + fo);

    int s0 = 2 * t, s1 = 2 * t + 1;
    float g0 = gslot[s0], g1 = gslot[s1];
    int e0 = eslot[s0], e1 = eslot[s1];
    size_t mo0 = (size_t)s0 * DMOD + d, mo1 = (size_t)s1 * DMOD + d;
    const u16* pm1 = pm + (size_t)2 * TTOK * DMOD;
    float4 ma = ld_bf4(pm + mo0), mb = ld_bf4(pm1 + mo0);
    float4 mc = ld_bf4(pm + mo1), md = ld_bf4(pm1 + mo1);
    float4 ba = *(const float4*)(b2 + e0 * DMOD + d);
    float4 bb = *(const float4*)(b2 + e1 * DMOD + d);

    float4 o;
    o.x = h.x + f0.x + f1.x + bias.x + a * (g0 * (ma.x + mb.x + ba.x) + g1 * (mc.x + md.x + bb.x));
    o.y = h.y + f0.y + f1.y + bias.y + a * (g0 * (ma.y + mb.y + ba.y) + g1 * (mc.y + md.y + bb.y));
    o.z = h.z + f0.z + f1.z + bias.z + a * (g0 * (ma.z + mb.z + ba.z) + g1 * (mc.z + md.z + bb.z));
    o.w = h.w + f0.w + f1.w + bias.w + a * (g0 * (ma.w + mb.w + ba.w) + g1 * (mc.w + md.w + bb.w));
    ((float4*)out)[i] = o;
}

extern "C" void kernel_launch(void* const* d_in, const int* in_sizes, int n_in,
                              void* d_out, int out_size, void* d_ws, size_t ws_size,
                              hipStream_t stream)
{
    const float* hidden   = (const float*)d_in[0];
    const float* raw      = (const float*)d_in[1];
    const float* ln_g     = (const float*)d_in[2];
    const float* ln_b     = (const float*)d_in[3];
    const float* pre_g    = (const float*)d_in[4];
    const float* pre_b    = (const float*)d_in[5];
    const float* feat_w   = (const float*)d_in[6];
    const float* feat_b   = (const float*)d_in[7];
    const float* film_w   = (const float*)d_in[8];
    const float* film_b   = (const float*)d_in[9];
    const float* router_w = (const float*)d_in[10];
    const float* router_b = (const float*)d_in[11];
    const float* w1       = (const float*)d_in[12];
    const float* b1       = (const float*)d_in[13];
    const float* w2       = (const float*)d_in[14];
    const float* b2       = (const float*)d_in[15];
    const float* fc1_w    = (const float*)d_in[16];
    const float* fc1_b    = (const float*)d_in[17];
    const float* fc2_w    = (const float*)d_in[18];
    const float* fc2_b    = (const float*)d_in[19];
    const float* alpha    = (const float*)d_in[20];
    float* out = (float*)d_out;

    char* w = (char*)d_ws;
    auto alloc = [&](size_t b) { char* p = w; w += (b + 255) & ~(size_t)255; return p; };
    u16*  fc1t = (u16*)alloc((size_t)DFFN * DMOD * 2);
    u16*  fc2t = (u16*)alloc((size_t)DMOD * DFFN * 2);
    u16*  w1t  = (u16*)alloc((size_t)NEXP * HEXP * DMOD * 2);
    u16*  w2t  = (u16*)alloc((size_t)NEXP * DMOD * HEXP * 2);
    u16*  xs   = (u16*)alloc((size_t)TTOK * DMOD * 2);
    u16*  xin  = (u16*)alloc((size_t)TTOK * DMOD * 2);
    u16*  h1   = (u16*)alloc((size_t)TTOK * DFFN * 2);
    u16*  hb   = (u16*)alloc((size_t)2 * TTOK * HEXP * 2);
    u16*  pf   = (u16*)alloc((size_t)2 * TTOK * DMOD * 2);        // ffn2 partials (2 splits)
    u16*  pm   = (u16*)alloc((size_t)2 * 2 * TTOK * DMOD * 2);    // moe2 partials (2 splits)
    int*   cnt   = (int*)alloc(NEXP * 4);
    int*   slots = (int*)alloc((size_t)NEXP * TTOK * 4);
    float* gslot = (float*)alloc((size_t)2 * TTOK * 4);
    int*   eslot = (int*)alloc((size_t)2 * TTOK * 4);
    float* xbuf  = (float*)pm;      // fp32 [T,D]=8MB, consumed by film before stage2 writes pm
    float* featbuf = (float*)h1;    // 1MB, consumed by film before stage1 writes h1

    hipMemsetAsync(cnt, 0, NEXP * 4, stream);
    transpose_all<<<10240, 256, 0, stream>>>(fc1_w, fc2_w, w1, w2, fc1t, fc2t, w1t, w2t);
    prep_kernel<<<4096, 256, 0, stream>>>(hidden, raw, ln_g, ln_b, pre_g, pre_b,
        feat_w, feat_b, router_w, router_b, xs, xbuf, featbuf, cnt, slots, gslot, eslot);
    film_kernel<<<512, 256, 0, stream>>>(xbuf, featbuf, film_w, film_b, xin);
    stage1_kernel<<<dim3(32, 16, 9), 256, 0, stream>>>(xs, fc1t, fc1_b, h1,
        xin, w1t, b1, cnt, slots, hb);
    stage2_kernel<<<dim3(32, 8, 9), 256, 0, stream>>>(h1, fc2t, hb, w2t, cnt, slots, pf, pm);
    combine_kernel<<<2048, 256, 0, stream>>>(hidden, pf, pm, fc2_b, b2, gslot, eslot, alpha, out);
}

// Round 7
// 333.564 us; speedup vs baseline: 1.9174x; 1.7999x over previous
//
#include <hip/hip_runtime.h>
#include <hip/hip_bf16.h>

typedef __attribute__((ext_vector_type(8))) short short8;
typedef __attribute__((ext_vector_type(4))) float f32x4;
typedef unsigned short u16;

#define TTOK 4096
#define DMOD 512
#define DFFN 2048
#define NEXP 8
#define HEXP 1024

__device__ __forceinline__ u16 to_bf16(float f) {
    union { __hip_bfloat16 h; u16 u; } cv;
    cv.h = __float2bfloat16(f);
    return cv.u;
}

__device__ __forceinline__ float gelu_tanh(float x) {
    const float c = 0.7978845608028654f;
    float y = c * (x + 0.044715f * x * x * x);
    return x / (1.0f + __expf(-2.0f * y));
}

__device__ __forceinline__ float4 ld_bf4(const u16* p) {
    ushort4 u = *(const ushort4*)p;
    union { unsigned i; float f; } a, b, c, d;
    a.i = (unsigned)u.x << 16; b.i = (unsigned)u.y << 16;
    c.i = (unsigned)u.z << 16; d.i = (unsigned)u.w << 16;
    return make_float4(a.f, b.f, c.f, d.f);
}

__device__ __forceinline__ void gload16(const u16* g, u16* l) {
    __builtin_amdgcn_global_load_lds(
        (__attribute__((address_space(1))) void*)g,
        (__attribute__((address_space(3))) void*)l, 16, 0, 0);
}

// ---------------- pack weights fp32 [K,N] -> bf16 fragment-linear ----------------
// Packed unit u (16B, 8 elems): u = (f*S + s)*64 + lane; lane = q*16 + rr.
// elem j of unit: W[k = s*32 + q*8 + j][n = f*16 + rr].
// A B-frag load in the GEMM = uniform base + lane*16B -> one coalesced 1KB per wave.
__global__ __launch_bounds__(256) void pack_weights(
    const float* __restrict__ fc1_w, const float* __restrict__ fc2_w,
    const float* __restrict__ w1, const float* __restrict__ w2,
    u16* __restrict__ fc1p, u16* __restrict__ fc2p,
    u16* __restrict__ w1p, u16* __restrict__ w2p)
{
    int t = blockIdx.x * 256 + threadIdx.x;   // one 16B unit
    const float* src; u16* dst; int N, k, n;
    if (t < 131072) {             // fc1: F=128 S=16 N=2048
        int u = t; int lane = u & 63; int fs = u >> 6; int s = fs & 15;
        int q = lane >> 4, rr = lane & 15;
        src = fc1_w; dst = fc1p + (size_t)u * 8; N = 2048;
        k = s * 32 + q * 8; n = ((fs >> 4) * 16) + rr;
    } else if (t < 262144) {      // fc2: F=32 S=64 N=512
        int u = t - 131072; int lane = u & 63; int fs = u >> 6; int s = fs & 63;
        int q = lane >> 4, rr = lane & 15;
        src = fc2_w; dst = fc2p + (size_t)u * 8; N = 512;
        k = s * 32 + q * 8; n = ((fs >> 6) * 16) + rr;
    } else if (t < 786432) {      // w1: 8 experts, F=64 S=16 N=1024
        int u = t - 262144; int e = u >> 16; int v = u & 65535;
        int lane = v & 63; int fs = v >> 6; int s = fs & 15;
        int q = lane >> 4, rr = lane & 15;
        src = w1 + (size_t)e * 524288; dst = w1p + (size_t)u * 8; N = 1024;
        k = s * 32 + q * 8; n = ((fs >> 4) * 16) + rr;
    } else {                      // w2: 8 experts, F=32 S=32 N=512
        int u = t - 786432; int e = u >> 16; int v = u & 65535;
        int lane = v & 63; int fs = v >> 6; int s = fs & 31;
        int q = lane >> 4, rr = lane & 15;
        src = w2 + (size_t)e * 524288; dst = w2p + (size_t)u * 8; N = 512;
        k = s * 32 + q * 8; n = ((fs >> 5) * 16) + rr;
    }
    u16 ov[8];
#pragma unroll
    for (int j = 0; j < 8; ++j)
        ov[j] = to_bf16(src[(size_t)(k + j) * N + n]);
    *(uint4*)dst = *(uint4*)ov;
}

// ---------------- prep: LN(x2) + feat + router top-2 + bucketing ----------------
__global__ __launch_bounds__(256) void prep_kernel(
    const float* __restrict__ hidden, const float* __restrict__ raw,
    const float* __restrict__ ln_g, const float* __restrict__ ln_b,
    const float* __restrict__ pre_g, const float* __restrict__ pre_b,
    const float* __restrict__ feat_w, const float* __restrict__ feat_b,
    const float* __restrict__ router_w, const float* __restrict__ router_b,
    u16* __restrict__ xs, float* __restrict__ xbuf, float* __restrict__ featbuf,
    int* __restrict__ cnt, int* __restrict__ slots,
    float* __restrict__ gslot, int* __restrict__ eslot)
{
    const int t = blockIdx.x, tid = threadIdx.x;
    const int lane = tid & 63, wid = tid >> 6;
    __shared__ float sred[4], qred[4], raw_sh[16], logit_sh[8], plred[4][8];

    const float* hrow = hidden + (size_t)t * DMOD;
    float h0 = hrow[tid], h1 = hrow[tid + 256];
    float s = h0 + h1, q = h0 * h0 + h1 * h1;
#pragma unroll
    for (int off = 32; off > 0; off >>= 1) { s += __shfl_down(s, off); q += __shfl_down(q, off); }
    if (lane == 0) { sred[wid] = s; qred[wid] = q; }
    if (tid < 16) raw_sh[tid] = raw[(size_t)t * 16 + tid];
    __syncthreads();

    float mean = (sred[0] + sred[1] + sred[2] + sred[3]) * (1.0f / 512.0f);
    float var  = (qred[0] + qred[1] + qred[2] + qred[3]) * (1.0f / 512.0f) - mean * mean;
    float rstd = rsqrtf(var + 1e-5f);
    float xn0 = (h0 - mean) * rstd, xn1 = (h1 - mean) * rstd;
    float x0 = xn0 * ln_g[tid] + ln_b[tid];
    float x1 = xn1 * ln_g[tid + 256] + ln_b[tid + 256];
    xs[(size_t)t * DMOD + tid]       = to_bf16(xn0 * pre_g[tid] + pre_b[tid]);
    xs[(size_t)t * DMOD + tid + 256] = to_bf16(xn1 * pre_g[tid + 256] + pre_b[tid + 256]);
    xbuf[(size_t)t * DMOD + tid]       = x0;
    xbuf[(size_t)t * DMOD + tid + 256] = x1;

    float pl[8];
#pragma unroll
    for (int e = 0; e < 8; ++e)
        pl[e] = x0 * router_w[tid * 8 + e] + x1 * router_w[(tid + 256) * 8 + e];
#pragma unroll
    for (int e = 0; e < 8; ++e) {
        float v = pl[e];
#pragma unroll
        for (int off = 32; off > 0; off >>= 1) v += __shfl_down(v, off);
        if (lane == 0) plred[wid][e] = v;
    }

    if (tid < 64) {
        float fv = feat_b[tid];
#pragma unroll
        for (int f = 0; f < 16; ++f) fv += raw_sh[f] * feat_w[f * 64 + tid];
        featbuf[(size_t)t * 64 + tid] = fv;
    }
    __syncthreads();
    if (tid < 8)
        logit_sh[tid] = plred[0][tid] + plred[1][tid] + plred[2][tid] + plred[3][tid] + router_b[tid];
    __syncthreads();

    if (tid == 0) {
        float v0 = -1e30f, v1 = -1e30f; int i0 = 0, i1 = 0;
#pragma unroll
        for (int e = 0; e < 8; ++e) {
            float v = logit_sh[e];
            if (v > v0) { v1 = v0; i1 = i0; v0 = v; i0 = e; }
            else if (v > v1) { v1 = v; i1 = e; }
        }
        float g1 = 1.0f / (1.0f + __expf(v0 - v1));
        float g0 = 1.0f - g1;
        int p0 = atomicAdd(&cnt[i0], 1);
        slots[i0 * TTOK + p0] = 2 * t;
        int p1 = atomicAdd(&cnt[i1], 1);
        slots[i1 * TTOK + p1] = 2 * t + 1;
        gslot[2 * t] = g0;     eslot[2 * t] = i0;
        gslot[2 * t + 1] = g1; eslot[2 * t + 1] = i1;
    }
}

// ---------------- film: 8 tokens/block (bounded live set, no spill) ----------------
__global__ __launch_bounds__(256) void film_kernel(
    const float* __restrict__ xbuf, const float* __restrict__ featbuf,
    const float* __restrict__ film_w, const float* __restrict__ film_b,
    u16* __restrict__ xin)
{
    const int t0 = blockIdx.x * 8, tid = threadIdx.x;
    __shared__ float fs[8 * 64];
#pragma unroll
    for (int i = 0; i < 2; ++i)
        fs[tid + i * 256] = featbuf[(size_t)t0 * 64 + tid + i * 256];
    __syncthreads();

    float acc[8][4];
#pragma unroll
    for (int t = 0; t < 8; ++t) { acc[t][0] = 0.f; acc[t][1] = 0.f; acc[t][2] = 0.f; acc[t][3] = 0.f; }

    for (int j = 0; j < 64; ++j) {
        const float* fw = film_w + (size_t)j * 1024 + tid;
        float w0 = fw[0], w1 = fw[256], w2 = fw[512], w3 = fw[768];
#pragma unroll
        for (int t = 0; t < 8; ++t) {
            float fv = fs[t * 64 + j];
            acc[t][0] += fv * w0; acc[t][1] += fv * w1;
            acc[t][2] += fv * w2; acc[t][3] += fv * w3;
        }
    }
    float b0 = film_b[tid], b1 = film_b[tid + 256], b2 = film_b[tid + 512], b3 = film_b[tid + 768];
#pragma unroll
    for (int t = 0; t < 8; ++t) {
        size_t row = (size_t)(t0 + t) * DMOD;
        float xv0 = xbuf[row + tid], xv1 = xbuf[row + tid + 256];
        xin[row + tid]       = to_bf16(xv0 * (1.0f + acc[t][0] + b0) + acc[t][2] + b2);
        xin[row + tid + 256] = to_bf16(xv1 * (1.0f + acc[t][1] + b1) + acc[t][3] + b3);
    }
}

// ---------------- A-stationary GEMM core ----------------
// Block: 32 A-rows (LDS, XOR-swizzled, DMA-staged once per 512-K chunk), 256 output cols
// (wave w owns 64 = 4 frags, f0 = nfrag_base + w*4). B is packed fragment-linear: one
// wave load = uniform base + lane*16B (perfectly coalesced 1KB, L2-hot weights).
// K-loop has NO barriers: 2 ds_read + 4 B-loads (depth-1 prefetch) + 8 MFMA per step.
template<int KCHUNKS>
__device__ __forceinline__ void gemm32(
    const u16* const rp[8],   // global row base ptrs (elem units) for rows w*8+i, at k-chunk 0
    const u16* Bf0, int S, int sbase,  // packed B at frag f0; S = K_total/32; first step
    f32x4 acc[2][4], u16* As)
{
    const int tid = threadIdx.x, lane = tid & 63, w = tid >> 6;
    const int q = lane >> 4, rr = lane & 15, l7 = lane & 7;
#pragma unroll
    for (int mi = 0; mi < 2; ++mi)
#pragma unroll
        for (int nj = 0; nj < 4; ++nj) {
            acc[mi][nj][0] = 0.f; acc[mi][nj][1] = 0.f;
            acc[mi][nj][2] = 0.f; acc[mi][nj][3] = 0.f;
        }
    const u16* Bi[4];
#pragma unroll
    for (int i = 0; i < 4; ++i)
        Bi[i] = Bf0 + ((size_t)i * S + sbase) * 512 + lane * 8;

    // stage chunk 0: wave w stages rows w*8..w*8+7; row r=w*8+i has XOR key i:
    // lane l fetches logical chunk l^i -> lands at phys chunk l.  [verified r3: 0 conflicts]
#pragma unroll
    for (int i = 0; i < 8; ++i)
        gload16(rp[i] + (lane ^ i) * 8, As + (w * 8 + i) * 512);
    __syncthreads();

    short8 bn[4];
#pragma unroll
    for (int i = 0; i < 4; ++i) bn[i] = *(const short8*)(Bi[i]);

    const int a0base = rr * 512, a1base = (16 + rr) * 512;
#pragma unroll
    for (int c = 0; c < KCHUNKS; ++c) {
#pragma unroll
        for (int sl = 0; sl < 16; ++sl) {
            short8 b0 = bn[0], b1 = bn[1], b2 = bn[2], b3 = bn[3];
            int nstep = c * 16 + sl + 1;
            if (nstep < KCHUNKS * 16) {
#pragma unroll
                for (int i = 0; i < 4; ++i)
                    bn[i] = *(const short8*)(Bi[i] + (size_t)nstep * 512);
            }
            int pa = ((sl * 4 + q) ^ l7) * 8;
            short8 a0 = *(const short8*)(As + a0base + pa);
            short8 a1 = *(const short8*)(As + a1base + pa);
            acc[0][0] = __builtin_amdgcn_mfma_f32_16x16x32_bf16(a0, b0, acc[0][0], 0, 0, 0);
            acc[1][0] = __builtin_amdgcn_mfma_f32_16x16x32_bf16(a1, b0, acc[1][0], 0, 0, 0);
            acc[0][1] = __builtin_amdgcn_mfma_f32_16x16x32_bf16(a0, b1, acc[0][1], 0, 0, 0);
            acc[1][1] = __builtin_amdgcn_mfma_f32_16x16x32_bf16(a1, b1, acc[1][1], 0, 0, 0);
            acc[0][2] = __builtin_amdgcn_mfma_f32_16x16x32_bf16(a0, b2, acc[0][2], 0, 0, 0);
            acc[1][2] = __builtin_amdgcn_mfma_f32_16x16x32_bf16(a1, b2, acc[1][2], 0, 0, 0);
            acc[0][3] = __builtin_amdgcn_mfma_f32_16x16x32_bf16(a0, b3, acc[0][3], 0, 0, 0);
            acc[1][3] = __builtin_amdgcn_mfma_f32_16x16x32_bf16(a1, b3, acc[1][3], 0, 0, 0);
        }
        if (c + 1 < KCHUNKS) {
            __syncthreads();
#pragma unroll
            for (int i = 0; i < 8; ++i)
                gload16(rp[i] + (c + 1) * 512 + (lane ^ i) * 8, As + (w * 8 + i) * 512);
            __syncthreads();
        }
    }
}

// ---------------- stage1: ffn1 (z==8, y=0..7) + moe1 (z<8, y=0..3) ----------------
__global__ __launch_bounds__(256) void stage1_kernel(
    const u16* __restrict__ xs, const u16* __restrict__ fc1p, const float* __restrict__ fc1_b,
    u16* __restrict__ h1,
    const u16* __restrict__ xin, const u16* __restrict__ w1p, const float* __restrict__ b1,
    const int* __restrict__ cnt, const int* __restrict__ slots, u16* __restrict__ hbuf)
{
    __shared__ __align__(16) u16 As[16384];
    const int tid = threadIdx.x, lane = tid & 63, w = tid >> 6;
    const int cb = lane & 15, rq = (lane >> 4) * 4;
    const int m0 = blockIdx.x * 32;
    const u16* rp[8];
    f32x4 acc[2][4];

    if (blockIdx.z == 8) {
        const int f0 = blockIdx.y * 16 + w * 4;
#pragma unroll
        for (int i = 0; i < 8; ++i) rp[i] = xs + (size_t)(m0 + w * 8 + i) * 512;
        gemm32<1>(rp, fc1p + (size_t)f0 * 8192, 16, 0, acc, As);
#pragma unroll
        for (int mi = 0; mi < 2; ++mi)
#pragma unroll
            for (int nj = 0; nj < 4; ++nj) {
                int col = (f0 + nj) * 16 + cb;
                float bias = fc1_b[col];
#pragma unroll
                for (int r = 0; r < 4; ++r) {
                    int row = m0 + mi * 16 + rq + r;
                    h1[(size_t)row * DFFN + col] = to_bf16(gelu_tanh(acc[mi][nj][r] + bias));
                }
            }
    } else {
        if (blockIdx.y >= 4) return;
        const int e = blockIdx.z, ce = cnt[e];
        if (m0 >= ce) return;
        const int* sl = slots + e * TTOK;
        const int f0 = blockIdx.y * 16 + w * 4;
#pragma unroll
        for (int i = 0; i < 8; ++i) {
            int p = m0 + w * 8 + i; if (p > ce - 1) p = ce - 1;
            rp[i] = xin + (size_t)(sl[p] >> 1) * 512;
        }
        gemm32<1>(rp, w1p + (size_t)e * 524288 + (size_t)f0 * 8192, 16, 0, acc, As);
#pragma unroll
        for (int mi = 0; mi < 2; ++mi)
#pragma unroll
            for (int r = 0; r < 4; ++r) {
                int p = m0 + mi * 16 + rq + r;
                if (p < ce) {
                    int slot = sl[p];
#pragma unroll
                    for (int nj = 0; nj < 4; ++nj) {
                        int col = (f0 + nj) * 16 + cb;
                        hbuf[(size_t)slot * HEXP + col] = to_bf16(gelu_tanh(acc[mi][nj][r] + b1[e * HEXP + col]));
                    }
                }
            }
    }
}

// ---------------- stage2: ffn2 (z==8) + moe2 (z<8); y = nb*2 + ks ----------------
__global__ __launch_bounds__(256) void stage2_kernel(
    const u16* __restrict__ h1, const u16* __restrict__ fc2p,
    const u16* __restrict__ hbuf, const u16* __restrict__ w2p,
    const int* __restrict__ cnt, const int* __restrict__ slots,
    u16* __restrict__ pf, u16* __restrict__ pm)
{
    __shared__ __align__(16) u16 As[16384];
    const int tid = threadIdx.x, lane = tid & 63, w = tid >> 6;
    const int cb = lane & 15, rq = (lane >> 4) * 4;
    const int m0 = blockIdx.x * 32;
    const int ks = blockIdx.y & 1, nb = blockIdx.y >> 1;
    const int f0 = nb * 16 + w * 4;
    const u16* rp[8];
    f32x4 acc[2][4];

    if (blockIdx.z == 8) {
#pragma unroll
        for (int i = 0; i < 8; ++i)
            rp[i] = h1 + (size_t)(m0 + w * 8 + i) * DFFN + ks * 1024;
        gemm32<2>(rp, fc2p + (size_t)f0 * 32768, 64, ks * 32, acc, As);
        u16* dst = pf + (size_t)ks * TTOK * DMOD;
#pragma unroll
        for (int mi = 0; mi < 2; ++mi)
#pragma unroll
            for (int nj = 0; nj < 4; ++nj) {
                int col = (f0 + nj) * 16 + cb;
#pragma unroll
                for (int r = 0; r < 4; ++r) {
                    int row = m0 + mi * 16 + rq + r;
                    dst[(size_t)row * DMOD + col] = to_bf16(acc[mi][nj][r]);
                }
            }
    } else {
        const int e = blockIdx.z, ce = cnt[e];
        if (m0 >= ce) return;
        const int* sl = slots + e * TTOK;
#pragma unroll
        for (int i = 0; i < 8; ++i) {
            int p = m0 + w * 8 + i; if (p > ce - 1) p = ce - 1;
            rp[i] = hbuf + (size_t)sl[p] * HEXP + ks * 512;
        }
        gemm32<1>(rp, w2p + (size_t)e * 524288 + (size_t)f0 * 16384, 32, ks * 16, acc, As);
        u16* dst = pm + (size_t)ks * 2 * TTOK * DMOD;
#pragma unroll
        for (int mi = 0; mi < 2; ++mi)
#pragma unroll
            for (int r = 0; r < 4; ++r) {
                int p = m0 + mi * 16 + rq + r;
                if (p < ce) {
                    int slot = sl[p];
#pragma unroll
                    for (int nj = 0; nj < 4; ++nj) {
                        int col = (f0 + nj) * 16 + cb;
                        dst[(size_t)slot * DMOD + col] = to_bf16(acc[mi][nj][r]);
                    }
                }
            }
    }
}

// ---------------- combine: out = hidden + ffn2(+bias) + alpha*(gated moe(+bias)) ----------------
__global__ __launch_bounds__(256) void combine_kernel(
    const float* __restrict__ hidden, const u16* __restrict__ pf, const u16* __restrict__ pm,
    const float* __restrict__ fc2_b, const float* __restrict__ b2,
    const float* __restrict__ gslot, const int* __restrict__ eslot,
    const float* __restrict__ alpha, float* __restrict__ out)
{
    int i = blockIdx.x * 256 + threadIdx.x;     // float4 index over T*D/4
    int t = i >> 7, d = (i & 127) * 4;
    float a = alpha[0];
    float4 h = ((const float4*)hidden)[i];
    float4 bias = *(const float4*)(fc2_b + d);

    size_t fo = (size_t)t * DMOD + d;
    float4 f0 = ld_bf4(pf + fo), f1 = ld_bf4(pf + (size_t)TTOK * DMOD + fo);

    int s0 = 2 * t, s1 = 2 * t + 1;
    float g0 = gslot[s0], g1 = gslot[s1];
    int e0 = eslot[s0], e1 = eslot[s1];
    size_t mo0 = (size_t)s0 * DMOD + d, mo1 = (size_t)s1 * DMOD + d;
    const u16* pm1 = pm + (size_t)2 * TTOK * DMOD;
    float4 ma = ld_bf4(pm + mo0), mb = ld_bf4(pm1 + mo0);
    float4 mc = ld_bf4(pm + mo1), md = ld_bf4(pm1 + mo1);
    float4 ba = *(const float4*)(b2 + e0 * DMOD + d);
    float4 bb = *(const float4*)(b2 + e1 * DMOD + d);

    float4 o;
    o.x = h.x + f0.x + f1.x + bias.x + a * (g0 * (ma.x + mb.x + ba.x) + g1 * (mc.x + md.x + bb.x));
    o.y = h.y + f0.y + f1.y + bias.y + a * (g0 * (ma.y + mb.y + ba.y) + g1 * (mc.y + md.y + bb.y));
    o.z = h.z + f0.z + f1.z + bias.z + a * (g0 * (ma.z + mb.z + ba.z) + g1 * (mc.z + md.z + bb.z));
    o.w = h.w + f0.w + f1.w + bias.w + a * (g0 * (ma.w + mb.w + ba.w) + g1 * (mc.w + md.w + bb.w));
    ((float4*)out)[i] = o;
}

extern "C" void kernel_launch(void* const* d_in, const int* in_sizes, int n_in,
                              void* d_out, int out_size, void* d_ws, size_t ws_size,
                              hipStream_t stream)
{
    const float* hidden   = (const float*)d_in[0];
    const float* raw      = (const float*)d_in[1];
    const float* ln_g     = (const float*)d_in[2];
    const float* ln_b     = (const float*)d_in[3];
    const float* pre_g    = (const float*)d_in[4];
    const float* pre_b    = (const float*)d_in[5];
    const float* feat_w   = (const float*)d_in[6];
    const float* feat_b   = (const float*)d_in[7];
    const float* film_w   = (const float*)d_in[8];
    const float* film_b   = (const float*)d_in[9];
    const float* router_w = (const float*)d_in[10];
    const float* router_b = (const float*)d_in[11];
    const float* w1       = (const float*)d_in[12];
    const float* b1       = (const float*)d_in[13];
    const float* w2       = (const float*)d_in[14];
    const float* b2       = (const float*)d_in[15];
    const float* fc1_w    = (const float*)d_in[16];
    const float* fc1_b    = (const float*)d_in[17];
    const float* fc2_w    = (const float*)d_in[18];
    const float* fc2_b    = (const float*)d_in[19];
    const float* alpha    = (const float*)d_in[20];
    float* out = (float*)d_out;

    char* w = (char*)d_ws;
    auto alloc = [&](size_t b) { char* p = w; w += (b + 255) & ~(size_t)255; return p; };
    u16*  fc1p = (u16*)alloc((size_t)DFFN * DMOD * 2);
    u16*  fc2p = (u16*)alloc((size_t)DMOD * DFFN * 2);
    u16*  w1p  = (u16*)alloc((size_t)NEXP * HEXP * DMOD * 2);
    u16*  w2p  = (u16*)alloc((size_t)NEXP * DMOD * HEXP * 2);
    u16*  xs   = (u16*)alloc((size_t)TTOK * DMOD * 2);
    u16*  xin  = (u16*)alloc((size_t)TTOK * DMOD * 2);
    u16*  h1   = (u16*)alloc((size_t)TTOK * DFFN * 2);
    u16*  hb   = (u16*)alloc((size_t)2 * TTOK * HEXP * 2);
    u16*  pf   = (u16*)alloc((size_t)2 * TTOK * DMOD * 2);        // ffn2 partials (2 splits)
    u16*  pm   = (u16*)alloc((size_t)2 * 2 * TTOK * DMOD * 2);    // moe2 partials (2 splits)
    int*   cnt   = (int*)alloc(NEXP * 4);
    int*   slots = (int*)alloc((size_t)NEXP * TTOK * 4);
    float* gslot = (float*)alloc((size_t)2 * TTOK * 4);
    int*   eslot = (int*)alloc((size_t)2 * TTOK * 4);
    float* xbuf  = (float*)pm;      // fp32 [T,D]=8MB, consumed by film before stage2 writes pm
    float* featbuf = (float*)h1;    // 1MB, consumed by film before stage1 writes h1

    hipMemsetAsync(cnt, 0, NEXP * 4, stream);
    pack_weights<<<5120, 256, 0, stream>>>(fc1_w, fc2_w, w1, w2, fc1p, fc2p, w1p, w2p);
    prep_kernel<<<4096, 256, 0, stream>>>(hidden, raw, ln_g, ln_b, pre_g, pre_b,
        feat_w, feat_b, router_w, router_b, xs, xbuf, featbuf, cnt, slots, gslot, eslot);
    film_kernel<<<512, 256, 0, stream>>>(xbuf, featbuf, film_w, film_b, xin);
    stage1_kernel<<<dim3(128, 8, 9), 256, 0, stream>>>(xs, fc1p, fc1_b, h1,
        xin, w1p, b1, cnt, slots, hb);
    stage2_kernel<<<dim3(128, 4, 9), 256, 0, stream>>>(h1, fc2p, hb, w2p, cnt, slots, pf, pm);
    combine_kernel<<<2048, 256, 0, stream>>>(hidden, pf, pm, fc2_b, b2, gslot, eslot, alpha, out);
}

// Round 8
// 252.494 us; speedup vs baseline: 2.5330x; 1.3211x over previous
//
#include <hip/hip_runtime.h>
#include <hip/hip_bf16.h>

typedef __attribute__((ext_vector_type(8))) short short8;
typedef __attribute__((ext_vector_type(4))) float f32x4;
typedef unsigned short u16;

#define TTOK 4096
#define DMOD 512
#define DFFN 2048
#define NEXP 8
#define HEXP 1024

__device__ __forceinline__ u16 to_bf16(float f) {
    union { __hip_bfloat16 h; u16 u; } cv;
    cv.h = __float2bfloat16(f);
    return cv.u;
}

__device__ __forceinline__ float gelu_tanh(float x) {
    const float c = 0.7978845608028654f;
    float y = c * (x + 0.044715f * x * x * x);
    return x / (1.0f + __expf(-2.0f * y));
}

__device__ __forceinline__ float4 ld_bf4(const u16* p) {
    ushort4 u = *(const ushort4*)p;
    union { unsigned i; float f; } a, b, c, d;
    a.i = (unsigned)u.x << 16; b.i = (unsigned)u.y << 16;
    c.i = (unsigned)u.z << 16; d.i = (unsigned)u.w << 16;
    return make_float4(a.f, b.f, c.f, d.f);
}

__device__ __forceinline__ void gload16(const u16* g, u16* l) {
    __builtin_amdgcn_global_load_lds(
        (__attribute__((address_space(1))) void*)g,
        (__attribute__((address_space(3))) void*)l, 16, 0, 0);
}

// ---------------- pack weights fp32 [K,N] -> bf16 fragment-linear ----------------
__global__ __launch_bounds__(256) void pack_weights(
    const float* __restrict__ fc1_w, const float* __restrict__ fc2_w,
    const float* __restrict__ w1, const float* __restrict__ w2,
    u16* __restrict__ fc1p, u16* __restrict__ fc2p,
    u16* __restrict__ w1p, u16* __restrict__ w2p)
{
    int t = blockIdx.x * 256 + threadIdx.x;   // one 16B unit
    const float* src; u16* dst; int N, k, n;
    if (t < 131072) {             // fc1: F=128 S=16 N=2048
        int u = t; int lane = u & 63; int fs = u >> 6; int s = fs & 15;
        int q = lane >> 4, rr = lane & 15;
        src = fc1_w; dst = fc1p + (size_t)u * 8; N = 2048;
        k = s * 32 + q * 8; n = ((fs >> 4) * 16) + rr;
    } else if (t < 262144) {      // fc2: F=32 S=64 N=512
        int u = t - 131072; int lane = u & 63; int fs = u >> 6; int s = fs & 63;
        int q = lane >> 4, rr = lane & 15;
        src = fc2_w; dst = fc2p + (size_t)u * 8; N = 512;
        k = s * 32 + q * 8; n = ((fs >> 6) * 16) + rr;
    } else if (t < 786432) {      // w1: 8 experts, F=64 S=16 N=1024
        int u = t - 262144; int e = u >> 16; int v = u & 65535;
        int lane = v & 63; int fs = v >> 6; int s = fs & 15;
        int q = lane >> 4, rr = lane & 15;
        src = w1 + (size_t)e * 524288; dst = w1p + (size_t)u * 8; N = 1024;
        k = s * 32 + q * 8; n = ((fs >> 4) * 16) + rr;
    } else {                      // w2: 8 experts, F=32 S=32 N=512
        int u = t - 786432; int e = u >> 16; int v = u & 65535;
        int lane = v & 63; int fs = v >> 6; int s = fs & 31;
        int q = lane >> 4, rr = lane & 15;
        src = w2 + (size_t)e * 524288; dst = w2p + (size_t)u * 8; N = 512;
        k = s * 32 + q * 8; n = ((fs >> 5) * 16) + rr;
    }
    u16 ov[8];
#pragma unroll
    for (int j = 0; j < 8; ++j)
        ov[j] = to_bf16(src[(size_t)(k + j) * N + n]);
    *(uint4*)dst = *(uint4*)ov;
}

// ---------------- ln: wave-per-token, lane-major; LN x2 + router logits + feat ----------------
// No __syncthreads (pure wave-synchronous). One butterfly (mean+var). Router partials in
// two named float4 accumulators (no array -> no scratch spill; r7 lesson: VGPR_Count=24
// meant pl[8] spilled and serialized the whole kernel).
__global__ __launch_bounds__(256) void ln_kernel(
    const float* __restrict__ hidden, const float* __restrict__ raw,
    const float* __restrict__ ln_g, const float* __restrict__ ln_b,
    const float* __restrict__ pre_g, const float* __restrict__ pre_b,
    const float* __restrict__ feat_w, const float* __restrict__ feat_b,
    const float* __restrict__ router_w, const float* __restrict__ router_b,
    u16* __restrict__ xs, float* __restrict__ xbuf, float* __restrict__ featbuf,
    float* __restrict__ logits)
{
    const int tid = threadIdx.x, lane = tid & 63, w = tid >> 6;
    const int t = blockIdx.x * 4 + w;
    __shared__ float pl8[4][64][8];
    __shared__ float raw_sh[4][16];

    const float* xrow = hidden + (size_t)t * DMOD + lane * 8;
    float4 xa = *(const float4*)(xrow);
    float4 xb = *(const float4*)(xrow + 4);
    if (lane < 16) raw_sh[w][lane] = raw[(size_t)t * 16 + lane];

    float s = xa.x + xa.y + xa.z + xa.w + xb.x + xb.y + xb.z + xb.w;
    float q = xa.x*xa.x + xa.y*xa.y + xa.z*xa.z + xa.w*xa.w
            + xb.x*xb.x + xb.y*xb.y + xb.z*xb.z + xb.w*xb.w;
#pragma unroll
    for (int m = 32; m > 0; m >>= 1) { s += __shfl_xor(s, m); q += __shfl_xor(q, m); }
    float mean = s * (1.0f / 512.0f);
    float var  = q * (1.0f / 512.0f) - mean * mean;
    float rstd = rsqrtf(var + 1e-5f);

    float4 na, nb;
    na.x = (xa.x - mean) * rstd; na.y = (xa.y - mean) * rstd;
    na.z = (xa.z - mean) * rstd; na.w = (xa.w - mean) * rstd;
    nb.x = (xb.x - mean) * rstd; nb.y = (xb.y - mean) * rstd;
    nb.z = (xb.z - mean) * rstd; nb.w = (xb.w - mean) * rstd;

    const int d8 = lane * 8;
    float4 pga = *(const float4*)(pre_g + d8), pgb = *(const float4*)(pre_g + d8 + 4);
    float4 pba = *(const float4*)(pre_b + d8), pbb = *(const float4*)(pre_b + d8 + 4);
    u16 ov[8];
    ov[0] = to_bf16(na.x * pga.x + pba.x); ov[1] = to_bf16(na.y * pga.y + pba.y);
    ov[2] = to_bf16(na.z * pga.z + pba.z); ov[3] = to_bf16(na.w * pga.w + pba.w);
    ov[4] = to_bf16(nb.x * pgb.x + pbb.x); ov[5] = to_bf16(nb.y * pgb.y + pbb.y);
    ov[6] = to_bf16(nb.z * pgb.z + pbb.z); ov[7] = to_bf16(nb.w * pgb.w + pbb.w);
    *(uint4*)(xs + (size_t)t * DMOD + d8) = *(uint4*)ov;

    float4 lga = *(const float4*)(ln_g + d8), lgb = *(const float4*)(ln_g + d8 + 4);
    float4 lba = *(const float4*)(ln_b + d8), lbb = *(const float4*)(ln_b + d8 + 4);
    float4 x03, x47;
    x03.x = na.x * lga.x + lba.x; x03.y = na.y * lga.y + lba.y;
    x03.z = na.z * lga.z + lba.z; x03.w = na.w * lga.w + lba.w;
    x47.x = nb.x * lgb.x + lbb.x; x47.y = nb.y * lgb.y + lbb.y;
    x47.z = nb.z * lgb.z + lbb.z; x47.w = nb.w * lgb.w + lbb.w;
    *(float4*)(xbuf + (size_t)t * DMOD + d8) = x03;
    *(float4*)(xbuf + (size_t)t * DMOD + d8 + 4) = x47;

    // router partials: lane owns dims d8..d8+7; accumulate into two float4 (8 experts)
    float4 p03 = make_float4(0.f, 0.f, 0.f, 0.f), p47 = p03;
    const float* rw = router_w + (size_t)d8 * 8;
#pragma unroll
    for (int j = 0; j < 8; ++j) {
        float xv = (j < 4) ? ((j == 0) ? x03.x : (j == 1) ? x03.y : (j == 2) ? x03.z : x03.w)
                           : ((j == 4) ? x47.x : (j == 5) ? x47.y : (j == 6) ? x47.z : x47.w);
        float4 r0 = *(const float4*)(rw + j * 8);
        float4 r1 = *(const float4*)(rw + j * 8 + 4);
        p03.x += xv * r0.x; p03.y += xv * r0.y; p03.z += xv * r0.z; p03.w += xv * r0.w;
        p47.x += xv * r1.x; p47.y += xv * r1.y; p47.z += xv * r1.z; p47.w += xv * r1.w;
    }
    *(float4*)(&pl8[w][lane][0]) = p03;
    *(float4*)(&pl8[w][lane][4]) = p47;
    // wave-synchronous: all lanes wrote above before any lane reads below (program order)
    if (lane < 8) {
        float acc = router_b[lane];
#pragma unroll 8
        for (int i = 0; i < 64; ++i) acc += pl8[w][i][lane];
        logits[(size_t)t * 8 + lane] = acc;
    }

    // feat encoder: one output per lane
    float fv = feat_b[lane];
#pragma unroll
    for (int f = 0; f < 16; ++f) fv += raw_sh[w][f] * feat_w[f * 64 + lane];
    featbuf[(size_t)t * 64 + lane] = fv;
}

// ---------------- bucket: top-2 + two-level (LDS hist + 8 global atomics/block) ----------------
__global__ __launch_bounds__(256) void bucket_kernel(
    const float* __restrict__ logits, int* __restrict__ cnt, int* __restrict__ slots,
    float* __restrict__ gslot, int* __restrict__ eslot)
{
    const int tid = threadIdx.x;
    const int t = blockIdx.x * 256 + tid;
    __shared__ int csh[8], base[8];
    if (tid < 8) csh[tid] = 0;
    __syncthreads();

    float4 l0 = *(const float4*)(logits + (size_t)t * 8);
    float4 l1 = *(const float4*)(logits + (size_t)t * 8 + 4);
    float v0 = -1e30f, v1 = -1e30f; int i0 = 0, i1 = 0;
#define CK(val, idx) { float v = (val); if (v > v0) { v1 = v0; i1 = i0; v0 = v; i0 = idx; } \
                       else if (v > v1) { v1 = v; i1 = idx; } }
    CK(l0.x, 0) CK(l0.y, 1) CK(l0.z, 2) CK(l0.w, 3)
    CK(l1.x, 4) CK(l1.y, 5) CK(l1.z, 6) CK(l1.w, 7)
#undef CK
    float g1 = 1.0f / (1.0f + __expf(v0 - v1));
    float g0 = 1.0f - g1;
    int r0 = atomicAdd(&csh[i0], 1);
    int r1 = atomicAdd(&csh[i1], 1);
    __syncthreads();
    if (tid < 8) base[tid] = atomicAdd(&cnt[tid], csh[tid]);
    __syncthreads();
    int p0 = base[i0] + r0, p1 = base[i1] + r1;
    slots[i0 * TTOK + p0] = 2 * t;
    slots[i1 * TTOK + p1] = 2 * t + 1;
    gslot[2 * t] = g0;     eslot[2 * t] = i0;
    gslot[2 * t + 1] = g1; eslot[2 * t + 1] = i1;
}

// ---------------- film: 8 tokens/block (bounded live set, no spill) ----------------
__global__ __launch_bounds__(256) void film_kernel(
    const float* __restrict__ xbuf, const float* __restrict__ featbuf,
    const float* __restrict__ film_w, const float* __restrict__ film_b,
    u16* __restrict__ xin)
{
    const int t0 = blockIdx.x * 8, tid = threadIdx.x;
    __shared__ float fs[8 * 64];
#pragma unroll
    for (int i = 0; i < 2; ++i)
        fs[tid + i * 256] = featbuf[(size_t)t0 * 64 + tid + i * 256];
    __syncthreads();

    float acc[8][4];
#pragma unroll
    for (int t = 0; t < 8; ++t) { acc[t][0] = 0.f; acc[t][1] = 0.f; acc[t][2] = 0.f; acc[t][3] = 0.f; }

    for (int j = 0; j < 64; ++j) {
        const float* fw = film_w + (size_t)j * 1024 + tid;
        float w0 = fw[0], w1 = fw[256], w2 = fw[512], w3 = fw[768];
#pragma unroll
        for (int t = 0; t < 8; ++t) {
            float fv = fs[t * 64 + j];
            acc[t][0] += fv * w0; acc[t][1] += fv * w1;
            acc[t][2] += fv * w2; acc[t][3] += fv * w3;
        }
    }
    float b0 = film_b[tid], b1 = film_b[tid + 256], b2 = film_b[tid + 512], b3 = film_b[tid + 768];
#pragma unroll
    for (int t = 0; t < 8; ++t) {
        size_t row = (size_t)(t0 + t) * DMOD;
        float xv0 = xbuf[row + tid], xv1 = xbuf[row + tid + 256];
        xin[row + tid]       = to_bf16(xv0 * (1.0f + acc[t][0] + b0) + acc[t][2] + b2);
        xin[row + tid + 256] = to_bf16(xv1 * (1.0f + acc[t][1] + b1) + acc[t][3] + b3);
    }
}

// ---------------- A-stationary GEMM core (r7: verified fast) ----------------
template<int KCHUNKS>
__device__ __forceinline__ void gemm32(
    const u16* const rp[8],
    const u16* Bf0, int S, int sbase,
    f32x4 acc[2][4], u16* As)
{
    const int tid = threadIdx.x, lane = tid & 63, w = tid >> 6;
    const int q = lane >> 4, rr = lane & 15, l7 = lane & 7;
#pragma unroll
    for (int mi = 0; mi < 2; ++mi)
#pragma unroll
        for (int nj = 0; nj < 4; ++nj) {
            acc[mi][nj][0] = 0.f; acc[mi][nj][1] = 0.f;
            acc[mi][nj][2] = 0.f; acc[mi][nj][3] = 0.f;
        }
    const u16* Bi[4];
#pragma unroll
    for (int i = 0; i < 4; ++i)
        Bi[i] = Bf0 + ((size_t)i * S + sbase) * 512 + lane * 8;

#pragma unroll
    for (int i = 0; i < 8; ++i)
        gload16(rp[i] + (lane ^ i) * 8, As + (w * 8 + i) * 512);
    __syncthreads();

    short8 bn[4];
#pragma unroll
    for (int i = 0; i < 4; ++i) bn[i] = *(const short8*)(Bi[i]);

    const int a0base = rr * 512, a1base = (16 + rr) * 512;
#pragma unroll
    for (int c = 0; c < KCHUNKS; ++c) {
#pragma unroll
        for (int sl = 0; sl < 16; ++sl) {
            short8 b0 = bn[0], b1 = bn[1], b2 = bn[2], b3 = bn[3];
            int nstep = c * 16 + sl + 1;
            if (nstep < KCHUNKS * 16) {
#pragma unroll
                for (int i = 0; i < 4; ++i)
                    bn[i] = *(const short8*)(Bi[i] + (size_t)nstep * 512);
            }
            int pa = ((sl * 4 + q) ^ l7) * 8;
            short8 a0 = *(const short8*)(As + a0base + pa);
            short8 a1 = *(const short8*)(As + a1base + pa);
            acc[0][0] = __builtin_amdgcn_mfma_f32_16x16x32_bf16(a0, b0, acc[0][0], 0, 0, 0);
            acc[1][0] = __builtin_amdgcn_mfma_f32_16x16x32_bf16(a1, b0, acc[1][0], 0, 0, 0);
            acc[0][1] = __builtin_amdgcn_mfma_f32_16x16x32_bf16(a0, b1, acc[0][1], 0, 0, 0);
            acc[1][1] = __builtin_amdgcn_mfma_f32_16x16x32_bf16(a1, b1, acc[1][1], 0, 0, 0);
            acc[0][2] = __builtin_amdgcn_mfma_f32_16x16x32_bf16(a0, b2, acc[0][2], 0, 0, 0);
            acc[1][2] = __builtin_amdgcn_mfma_f32_16x16x32_bf16(a1, b2, acc[1][2], 0, 0, 0);
            acc[0][3] = __builtin_amdgcn_mfma_f32_16x16x32_bf16(a0, b3, acc[0][3], 0, 0, 0);
            acc[1][3] = __builtin_amdgcn_mfma_f32_16x16x32_bf16(a1, b3, acc[1][3], 0, 0, 0);
        }
        if (c + 1 < KCHUNKS) {
            __syncthreads();
#pragma unroll
            for (int i = 0; i < 8; ++i)
                gload16(rp[i] + (c + 1) * 512 + (lane ^ i) * 8, As + (w * 8 + i) * 512);
            __syncthreads();
        }
    }
}

// ---------------- stage1: ffn1 (z==8, y=0..7) + moe1 (z<8, y=0..3) ----------------
__global__ __launch_bounds__(256) void stage1_kernel(
    const u16* __restrict__ xs, const u16* __restrict__ fc1p, const float* __restrict__ fc1_b,
    u16* __restrict__ h1,
    const u16* __restrict__ xin, const u16* __restrict__ w1p, const float* __restrict__ b1,
    const int* __restrict__ cnt, const int* __restrict__ slots, u16* __restrict__ hbuf)
{
    __shared__ __align__(16) u16 As[16384];
    const int tid = threadIdx.x, lane = tid & 63, w = tid >> 6;
    const int cb = lane & 15, rq = (lane >> 4) * 4;
    const int m0 = blockIdx.x * 32;
    const u16* rp[8];
    f32x4 acc[2][4];

    if (blockIdx.z == 8) {
        const int f0 = blockIdx.y * 16 + w * 4;
#pragma unroll
        for (int i = 0; i < 8; ++i) rp[i] = xs + (size_t)(m0 + w * 8 + i) * 512;
        gemm32<1>(rp, fc1p + (size_t)f0 * 8192, 16, 0, acc, As);
#pragma unroll
        for (int mi = 0; mi < 2; ++mi)
#pragma unroll
            for (int nj = 0; nj < 4; ++nj) {
                int col = (f0 + nj) * 16 + cb;
                float bias = fc1_b[col];
#pragma unroll
                for (int r = 0; r < 4; ++r) {
                    int row = m0 + mi * 16 + rq + r;
                    h1[(size_t)row * DFFN + col] = to_bf16(gelu_tanh(acc[mi][nj][r] + bias));
                }
            }
    } else {
        if (blockIdx.y >= 4) return;
        const int e = blockIdx.z, ce = cnt[e];
        if (m0 >= ce) return;
        const int* sl = slots + e * TTOK;
        const int f0 = blockIdx.y * 16 + w * 4;
#pragma unroll
        for (int i = 0; i < 8; ++i) {
            int p = m0 + w * 8 + i; if (p > ce - 1) p = ce - 1;
            rp[i] = xin + (size_t)(sl[p] >> 1) * 512;
        }
        gemm32<1>(rp, w1p + (size_t)e * 524288 + (size_t)f0 * 8192, 16, 0, acc, As);
#pragma unroll
        for (int mi = 0; mi < 2; ++mi)
#pragma unroll
            for (int r = 0; r < 4; ++r) {
                int p = m0 + mi * 16 + rq + r;
                if (p < ce) {
                    int slot = sl[p];
#pragma unroll
                    for (int nj = 0; nj < 4; ++nj) {
                        int col = (f0 + nj) * 16 + cb;
                        hbuf[(size_t)slot * HEXP + col] = to_bf16(gelu_tanh(acc[mi][nj][r] + b1[e * HEXP + col]));
                    }
                }
            }
    }
}

// ---------------- stage2: ffn2 (z==8) + moe2 (z<8); y = nb*2 + ks ----------------
__global__ __launch_bounds__(256) void stage2_kernel(
    const u16* __restrict__ h1, const u16* __restrict__ fc2p,
    const u16* __restrict__ hbuf, const u16* __restrict__ w2p,
    const int* __restrict__ cnt, const int* __restrict__ slots,
    u16* __restrict__ pf, u16* __restrict__ pm)
{
    __shared__ __align__(16) u16 As[16384];
    const int tid = threadIdx.x, lane = tid & 63, w = tid >> 6;
    const int cb = lane & 15, rq = (lane >> 4) * 4;
    const int m0 = blockIdx.x * 32;
    const int ks = blockIdx.y & 1, nb = blockIdx.y >> 1;
    const int f0 = nb * 16 + w * 4;
    const u16* rp[8];
    f32x4 acc[2][4];

    if (blockIdx.z == 8) {
#pragma unroll
        for (int i = 0; i < 8; ++i)
            rp[i] = h1 + (size_t)(m0 + w * 8 + i) * DFFN + ks * 1024;
        gemm32<2>(rp, fc2p + (size_t)f0 * 32768, 64, ks * 32, acc, As);
        u16* dst = pf + (size_t)ks * TTOK * DMOD;
#pragma unroll
        for (int mi = 0; mi < 2; ++mi)
#pragma unroll
            for (int nj = 0; nj < 4; ++nj) {
                int col = (f0 + nj) * 16 + cb;
#pragma unroll
                for (int r = 0; r < 4; ++r) {
                    int row = m0 + mi * 16 + rq + r;
                    dst[(size_t)row * DMOD + col] = to_bf16(acc[mi][nj][r]);
                }
            }
    } else {
        const int e = blockIdx.z, ce = cnt[e];
        if (m0 >= ce) return;
        const int* sl = slots + e * TTOK;
#pragma unroll
        for (int i = 0; i < 8; ++i) {
            int p = m0 + w * 8 + i; if (p > ce - 1) p = ce - 1;
            rp[i] = hbuf + (size_t)sl[p] * HEXP + ks * 512;
        }
        gemm32<1>(rp, w2p + (size_t)e * 524288 + (size_t)f0 * 16384, 32, ks * 16, acc, As);
        u16* dst = pm + (size_t)ks * 2 * TTOK * DMOD;
#pragma unroll
        for (int mi = 0; mi < 2; ++mi)
#pragma unroll
            for (int r = 0; r < 4; ++r) {
                int p = m0 + mi * 16 + rq + r;
                if (p < ce) {
                    int slot = sl[p];
#pragma unroll
                    for (int nj = 0; nj < 4; ++nj) {
                        int col = (f0 + nj) * 16 + cb;
                        dst[(size_t)slot * DMOD + col] = to_bf16(acc[mi][nj][r]);
                    }
                }
            }
    }
}

// ---------------- combine: out = hidden + ffn2(+bias) + alpha*(gated moe(+bias)) ----------------
__global__ __launch_bounds__(256) void combine_kernel(
    const float* __restrict__ hidden, const u16* __restrict__ pf, const u16* __restrict__ pm,
    const float* __restrict__ fc2_b, const float* __restrict__ b2,
    const float* __restrict__ gslot, const int* __restrict__ eslot,
    const float* __restrict__ alpha, float* __restrict__ out)
{
    int i = blockIdx.x * 256 + threadIdx.x;     // float4 index over T*D/4
    int t = i >> 7, d = (i & 127) * 4;
    float a = alpha[0];
    float4 h = ((const float4*)hidden)[i];
    float4 bias = *(const float4*)(fc2_b + d);

    size_t fo = (size_t)t * DMOD + d;
    float4 f0 = ld_bf4(pf + fo), f1 = ld_bf4(pf + (size_t)TTOK * DMOD + fo);

    int s0 = 2 * t, s1 = 2 * t + 1;
    float g0 = gslot[s0], g1 = gslot[s1];
    int e0 = eslot[s0], e1 = eslot[s1];
    size_t mo0 = (size_t)s0 * DMOD + d, mo1 = (size_t)s1 * DMOD + d;
    const u16* pm1 = pm + (size_t)2 * TTOK * DMOD;
    float4 ma = ld_bf4(pm + mo0), mb = ld_bf4(pm1 + mo0);
    float4 mc = ld_bf4(pm + mo1), md = ld_bf4(pm1 + mo1);
    float4 ba = *(const float4*)(b2 + e0 * DMOD + d);
    float4 bb = *(const float4*)(b2 + e1 * DMOD + d);

    float4 o;
    o.x = h.x + f0.x + f1.x + bias.x + a * (g0 * (ma.x + mb.x + ba.x) + g1 * (mc.x + md.x + bb.x));
    o.y = h.y + f0.y + f1.y + bias.y + a * (g0 * (ma.y + mb.y + ba.y) + g1 * (mc.y + md.y + bb.y));
    o.z = h.z + f0.z + f1.z + bias.z + a * (g0 * (ma.z + mb.z + ba.z) + g1 * (mc.z + md.z + bb.z));
    o.w = h.w + f0.w + f1.w + bias.w + a * (g0 * (ma.w + mb.w + ba.w) + g1 * (mc.w + md.w + bb.w));
    ((float4*)out)[i] = o;
}

extern "C" void kernel_launch(void* const* d_in, const int* in_sizes, int n_in,
                              void* d_out, int out_size, void* d_ws, size_t ws_size,
                              hipStream_t stream)
{
    const float* hidden   = (const float*)d_in[0];
    const float* raw      = (const float*)d_in[1];
    const float* ln_g     = (const float*)d_in[2];
    const float* ln_b     = (const float*)d_in[3];
    const float* pre_g    = (const float*)d_in[4];
    const float* pre_b    = (const float*)d_in[5];
    const float* feat_w   = (const float*)d_in[6];
    const float* feat_b   = (const float*)d_in[7];
    const float* film_w   = (const float*)d_in[8];
    const float* film_b   = (const float*)d_in[9];
    const float* router_w = (const float*)d_in[10];
    const float* router_b = (const float*)d_in[11];
    const float* w1       = (const float*)d_in[12];
    const float* b1       = (const float*)d_in[13];
    const float* w2       = (const float*)d_in[14];
    const float* b2       = (const float*)d_in[15];
    const float* fc1_w    = (const float*)d_in[16];
    const float* fc1_b    = (const float*)d_in[17];
    const float* fc2_w    = (const float*)d_in[18];
    const float* fc2_b    = (const float*)d_in[19];
    const float* alpha    = (const float*)d_in[20];
    float* out = (float*)d_out;

    char* w = (char*)d_ws;
    auto alloc = [&](size_t b) { char* p = w; w += (b + 255) & ~(size_t)255; return p; };
    u16*  fc1p = (u16*)alloc((size_t)DFFN * DMOD * 2);
    u16*  fc2p = (u16*)alloc((size_t)DMOD * DFFN * 2);
    u16*  w1p  = (u16*)alloc((size_t)NEXP * HEXP * DMOD * 2);
    u16*  w2p  = (u16*)alloc((size_t)NEXP * DMOD * HEXP * 2);
    u16*  xs   = (u16*)alloc((size_t)TTOK * DMOD * 2);
    u16*  xin  = (u16*)alloc((size_t)TTOK * DMOD * 2);
    u16*  h1   = (u16*)alloc((size_t)TTOK * DFFN * 2);
    u16*  hb   = (u16*)alloc((size_t)2 * TTOK * HEXP * 2);
    u16*  pf   = (u16*)alloc((size_t)2 * TTOK * DMOD * 2);
    u16*  pm   = (u16*)alloc((size_t)2 * 2 * TTOK * DMOD * 2);
    int*   cnt   = (int*)alloc(NEXP * 4);
    int*   slots = (int*)alloc((size_t)NEXP * TTOK * 4);
    float* gslot = (float*)alloc((size_t)2 * TTOK * 4);
    int*   eslot = (int*)alloc((size_t)2 * TTOK * 4);
    float* logits = (float*)alloc((size_t)TTOK * 8 * 4);
    float* xbuf  = (float*)pm;      // fp32 [T,D]=8MB, consumed by film before stage2 writes pm
    float* featbuf = (float*)h1;    // 1MB, consumed by film before stage1 writes h1

    hipMemsetAsync(cnt, 0, NEXP * 4, stream);
    pack_weights<<<5120, 256, 0, stream>>>(fc1_w, fc2_w, w1, w2, fc1p, fc2p, w1p, w2p);
    ln_kernel<<<1024, 256, 0, stream>>>(hidden, raw, ln_g, ln_b, pre_g, pre_b,
        feat_w, feat_b, router_w, router_b, xs, xbuf, featbuf, logits);
    bucket_kernel<<<16, 256, 0, stream>>>(logits, cnt, slots, gslot, eslot);
    film_kernel<<<512, 256, 0, stream>>>(xbuf, featbuf, film_w, film_b, xin);
    stage1_kernel<<<dim3(128, 8, 9), 256, 0, stream>>>(xs, fc1p, fc1_b, h1,
        xin, w1p, b1, cnt, slots, hb);
    stage2_kernel<<<dim3(128, 4, 9), 256, 0, stream>>>(h1, fc2p, hb, w2p, cnt, slots, pf, pm);
    combine_kernel<<<2048, 256, 0, stream>>>(hidden, pf, pm, fc2_b, b2, gslot, eslot, alpha, out);
}